// Round 3
// baseline (2017.214 us; speedup 1.0000x reference)
//
#include <hip/hip_runtime.h>
#include <stdint.h>

#define DEV static __device__ __forceinline__

typedef __attribute__((ext_vector_type(8))) uint16_t u16x8;
typedef __attribute__((ext_vector_type(4))) uint16_t u16x4;
typedef __attribute__((ext_vector_type(4))) float    f32x4;
typedef __attribute__((ext_vector_type(8))) __bf16   bf16x8;

typedef __attribute__((address_space(3))) void lds_void;
typedef __attribute__((address_space(1))) void gbl_void;

DEV float bf2f(uint16_t u){
  union { uint32_t i; float f; } v; v.i = ((uint32_t)u) << 16; return v.f;
}
DEV uint16_t f2bf(float f){        // RNE
  union { float f; uint32_t i; } v; v.f = f;
  uint32_t r = v.i + 0x7FFFu + ((v.i >> 16) & 1u);
  return (uint16_t)(r >> 16);
}
DEV f32x4 mfma16(u16x8 a, u16x8 b, f32x4 c){
  return __builtin_amdgcn_mfma_f32_16x16x32_bf16(
      __builtin_bit_cast(bf16x8, a), __builtin_bit_cast(bf16x8, b), c, 0, 0, 0);
}

// ---------------------------------------------------------------------------
// GEMM: out[M,N] = A[M,K](bf16, lda) @ W[N,K](f32)^T + bias[N](f32)
// 128x128 tile, BK=64, 256 thr (2x2 waves), 16x16x32 bf16 MFMA, f32 accum.
// A: global_load_lds w=16.  W: reg-staged fp32 -> cvt bf16 -> ds_write_b128.
// MODE 0: plain. MODE 2: exact GELU.
// ---------------------------------------------------------------------------
template<int MODE>
__global__ __launch_bounds__(256)
void te_gemm_ff(const uint16_t* __restrict__ A, int lda,
                const float* __restrict__ W, const float* __restrict__ bias,
                uint16_t* __restrict__ outB, int M, int N, int K)
{
  __shared__ uint16_t la[128 * 64];
  __shared__ uint16_t lb[128 * 64];
  const int tid = threadIdx.x;
  const int w = tid >> 6, l = tid & 63;
  const int lr = l & 15, lg = l >> 4;
  const int tm = blockIdx.y * 128, tn = blockIdx.x * 128;
  const int srow = l >> 3, scol = (l & 7) * 8;
  const int wr = (w >> 1) * 64, wc = (w & 1) * 64;
  const int sRow = tid >> 3, sC8 = (tid & 7) * 8;   // W-staging: 32 rows/pass

  f32x4 acc[4][4] = {};

  for (int k0 = 0; k0 < K; k0 += 64) {
    // A[128][64] -> LDS via async DMA
#pragma unroll
    for (int c = 0; c < 4; c++) {
      const int rb = (c * 4 + w) * 8;
      const uint16_t* ga = A + (size_t)(tm + rb + srow) * lda + (k0 + scol);
      __builtin_amdgcn_global_load_lds((gbl_void*)(uintptr_t)ga,
                                       (lds_void*)(la + rb * 64), 16, 0, 0);
    }
    // W[128][64] f32 -> bf16 -> LDS
#pragma unroll
    for (int p = 0; p < 4; p++) {
      const int row = p * 32 + sRow;
      const float* gw = W + (size_t)(tn + row) * K + (k0 + sC8);
      f32x4 w0 = *(const f32x4*)gw;
      f32x4 w1 = *(const f32x4*)(gw + 4);
      u16x8 wb;
#pragma unroll
      for (int e = 0; e < 4; e++) {
        wb[e]     = __builtin_bit_cast(uint16_t, (__bf16)w0[e]);
        wb[e + 4] = __builtin_bit_cast(uint16_t, (__bf16)w1[e]);
      }
      *(u16x8*)&lb[row * 64 + sC8] = wb;
    }
    __syncthreads();
#pragma unroll
    for (int kk = 0; kk < 2; kk++) {
      const int ko = kk * 32 + lg * 8;
      u16x8 af[4], bfr[4];
#pragma unroll
      for (int i = 0; i < 4; i++)
        af[i] = *(const u16x8*)&la[(wr + i * 16 + lr) * 64 + ko];
#pragma unroll
      for (int j = 0; j < 4; j++)
        bfr[j] = *(const u16x8*)&lb[(wc + j * 16 + lr) * 64 + ko];
#pragma unroll
      for (int i = 0; i < 4; i++)
#pragma unroll
        for (int j = 0; j < 4; j++)
          acc[i][j] = mfma16(af[i], bfr[j], acc[i][j]);
    }
    __syncthreads();
  }

  float bv[4];
#pragma unroll
  for (int j = 0; j < 4; j++) bv[j] = bias[tn + wc + j * 16 + lr];
#pragma unroll
  for (int i = 0; i < 4; i++)
#pragma unroll
    for (int j = 0; j < 4; j++)
#pragma unroll
      for (int r = 0; r < 4; r++) {
        const int row = tm + wr + i * 16 + lg * 4 + r;
        const int col = tn + wc + j * 16 + lr;
        float v = acc[i][j][r] + bv[j];
        if (MODE == 2) v = 0.5f * v * (1.0f + erff(v * 0.70710678118654752f));
        outB[(size_t)row * N + col] = f2bf(v);
      }
}

// ---------------------------------------------------------------------------
// Bottleneck GEMM: A[M,K] f32, W[N,K] f32 -> bf16 out + f32 out (both written)
// ---------------------------------------------------------------------------
__global__ __launch_bounds__(256)
void te_gemm32(const float* __restrict__ A, const float* __restrict__ W,
               const float* __restrict__ bias, uint16_t* __restrict__ outB,
               float* __restrict__ outF, int M, int N, int K)
{
  __shared__ uint16_t la[128 * 64];
  __shared__ uint16_t lb[128 * 64];
  const int tid = threadIdx.x;
  const int w = tid >> 6, l = tid & 63;
  const int lr = l & 15, lg = l >> 4;
  const int tm = blockIdx.y * 128, tn = blockIdx.x * 128;
  const int wr = (w >> 1) * 64, wc = (w & 1) * 64;
  const int sRow = tid >> 3, sC8 = (tid & 7) * 8;

  f32x4 acc[4][4] = {};

  for (int k0 = 0; k0 < K; k0 += 64) {
#pragma unroll
    for (int p = 0; p < 4; p++) {
      const int row = p * 32 + sRow;
      const float* ga = A + (size_t)(tm + row) * K + (k0 + sC8);
      const float* gw = W + (size_t)(tn + row) * K + (k0 + sC8);
      f32x4 a0 = *(const f32x4*)ga, a1 = *(const f32x4*)(ga + 4);
      f32x4 w0 = *(const f32x4*)gw, w1 = *(const f32x4*)(gw + 4);
      u16x8 ab, wb;
#pragma unroll
      for (int e = 0; e < 4; e++) {
        ab[e]     = __builtin_bit_cast(uint16_t, (__bf16)a0[e]);
        ab[e + 4] = __builtin_bit_cast(uint16_t, (__bf16)a1[e]);
        wb[e]     = __builtin_bit_cast(uint16_t, (__bf16)w0[e]);
        wb[e + 4] = __builtin_bit_cast(uint16_t, (__bf16)w1[e]);
      }
      *(u16x8*)&la[row * 64 + sC8] = ab;
      *(u16x8*)&lb[row * 64 + sC8] = wb;
    }
    __syncthreads();
#pragma unroll
    for (int kk = 0; kk < 2; kk++) {
      const int ko = kk * 32 + lg * 8;
      u16x8 af[4], bfr[4];
#pragma unroll
      for (int i = 0; i < 4; i++)
        af[i] = *(const u16x8*)&la[(wr + i * 16 + lr) * 64 + ko];
#pragma unroll
      for (int j = 0; j < 4; j++)
        bfr[j] = *(const u16x8*)&lb[(wc + j * 16 + lr) * 64 + ko];
#pragma unroll
      for (int i = 0; i < 4; i++)
#pragma unroll
        for (int j = 0; j < 4; j++)
          acc[i][j] = mfma16(af[i], bfr[j], acc[i][j]);
    }
    __syncthreads();
  }

  float bv[4];
#pragma unroll
  for (int j = 0; j < 4; j++) bv[j] = bias[tn + wc + j * 16 + lr];
#pragma unroll
  for (int i = 0; i < 4; i++)
#pragma unroll
    for (int j = 0; j < 4; j++)
#pragma unroll
      for (int r = 0; r < 4; r++) {
        const int row = tm + wr + i * 16 + lg * 4 + r;
        const int col = tn + wc + j * 16 + lr;
        const float v = acc[i][j][r] + bv[j];
        const size_t idx = (size_t)row * N + col;
        outB[idx] = f2bf(v);
        outF[idx] = v;
      }
}

// ---------------------------------------------------------------------------
// Fused attention over qkv [B*T, 3072] bf16 (q|k|v, 16 heads x 64).
// Block = (qt, h, b); 4 waves x 16 q-rows; online softmax; alibi bias.
// Output written IN-PLACE into the q region (safe: each block reads only its
// own q rows/cols into registers before writing them at the end).
// ---------------------------------------------------------------------------
__global__ __launch_bounds__(256)
void te_attn(uint16_t* __restrict__ qkv)
{
  __shared__ uint16_t kl[64 * 72];
  __shared__ uint16_t vt[64 * 72];
  __shared__ uint16_t pl[64 * 72];
  const int tid = threadIdx.x;
  const int w = tid >> 6, l = tid & 63;
  const int lr = l & 15, lg = l >> 4;
  const int qt = blockIdx.x, h = blockIdx.y, b = blockIdx.z;

  u16x8 qf[2];
  {
    const size_t qoff = ((size_t)(b * 512 + qt * 64 + w * 16 + lr)) * 3072 + h * 64 + lg * 8;
    qf[0] = *(const u16x8*)&qkv[qoff];
    qf[1] = *(const u16x8*)&qkv[qoff + 32];
  }
  const float slope = exp2f(-0.5f * (float)(h + 1));
  const float scale = 0.125f;
  const int iBase = qt * 64 + w * 16 + lg * 4;

  float m[4], sd[4];
  f32x4 acc[4] = {};
#pragma unroll
  for (int r = 0; r < 4; r++) { m[r] = -1e30f; sd[r] = 0.0f; }

  for (int jt = 0; jt < 512; jt += 64) {
#pragma unroll
    for (int cc = 0; cc < 2; cc++) {
      const int c = tid + cc * 256;
      const int j = c >> 3, d0 = (c & 7) * 8;
      const size_t rbase = ((size_t)(b * 512 + jt + j)) * 3072 + h * 64 + d0;
      u16x8 kv = *(const u16x8*)&qkv[rbase + 1024];
      *(u16x8*)&kl[j * 72 + d0] = kv;
      u16x8 vv = *(const u16x8*)&qkv[rbase + 2048];
#pragma unroll
      for (int e = 0; e < 8; e++) vt[(d0 + e) * 72 + j] = vv[e];
    }
    __syncthreads();

    f32x4 s[4] = {};
#pragma unroll
    for (int kk = 0; kk < 2; kk++) {
      const int ko = kk * 32 + lg * 8;
#pragma unroll
      for (int n = 0; n < 4; n++) {
        u16x8 kf = *(const u16x8*)&kl[(n * 16 + lr) * 72 + ko];
        s[n] = mfma16(qf[kk], kf, s[n]);
      }
    }
    float mt[4] = { -1e30f, -1e30f, -1e30f, -1e30f };
#pragma unroll
    for (int n = 0; n < 4; n++)
#pragma unroll
      for (int r = 0; r < 4; r++) {
        const int dj = (iBase + r) - (jt + n * 16 + lr);
        const float v = s[n][r] * scale - slope * fabsf((float)dj);
        s[n][r] = v;
        mt[r] = fmaxf(mt[r], v);
      }
#pragma unroll
    for (int r = 0; r < 4; r++)
#pragma unroll
      for (int msk = 1; msk < 16; msk <<= 1)
        mt[r] = fmaxf(mt[r], __shfl_xor(mt[r], msk, 16));
    float fac[4], rsum[4];
#pragma unroll
    for (int r = 0; r < 4; r++) {
      const float mn = fmaxf(m[r], mt[r]);
      fac[r] = __expf(m[r] - mn);
      m[r] = mn;
      rsum[r] = 0.0f;
    }
#pragma unroll
    for (int n = 0; n < 4; n++)
#pragma unroll
      for (int r = 0; r < 4; r++) {
        const float p = __expf(s[n][r] - m[r]);
        s[n][r] = p;
        rsum[r] += p;
      }
#pragma unroll
    for (int r = 0; r < 4; r++) {
#pragma unroll
      for (int msk = 1; msk < 16; msk <<= 1)
        rsum[r] += __shfl_xor(rsum[r], msk, 16);
      sd[r] = sd[r] * fac[r] + rsum[r];
    }
#pragma unroll
    for (int n = 0; n < 4; n++)
#pragma unroll
      for (int r = 0; r < 4; r++) acc[n][r] *= fac[r];

#pragma unroll
    for (int n = 0; n < 4; n++)
#pragma unroll
      for (int r = 0; r < 4; r++)
        pl[(w * 16 + lg * 4 + r) * 72 + n * 16 + lr] = f2bf(s[n][r]);

#pragma unroll
    for (int kk = 0; kk < 2; kk++) {
      const int ko = kk * 32 + lg * 8;
      u16x8 pf = *(const u16x8*)&pl[(w * 16 + lr) * 72 + ko];
#pragma unroll
      for (int n = 0; n < 4; n++) {
        u16x8 vf = *(const u16x8*)&vt[(n * 16 + lr) * 72 + ko];
        acc[n] = mfma16(pf, vf, acc[n]);
      }
    }
    __syncthreads();
  }

#pragma unroll
  for (int n = 0; n < 4; n++)
#pragma unroll
    for (int r = 0; r < 4; r++) {
      const int i = iBase + r;
      const int d = h * 64 + n * 16 + lr;
      qkv[((size_t)(b * 512 + i)) * 3072 + d] = f2bf(acc[n][r] / sd[r]);
    }
}

// ---------------------------------------------------------------------------
// LN: x = hres(f32) + delta(bf16); y = LN(x)*w + b (w,b f32)
// FINAL=0: writes hout (f32, aliases hres) and bout (bf16).
// FINAL=1: writes hout (f32 = d_out) only.
// ---------------------------------------------------------------------------
template<int FINAL>
__global__ __launch_bounds__(256)
void te_ln(const float* __restrict__ hres, const uint16_t* __restrict__ delta,
           const float* __restrict__ w, const float* __restrict__ b,
           float* __restrict__ hout, uint16_t* __restrict__ bout)
{
  const int row = blockIdx.x, t = threadIdx.x;
  const size_t base = (size_t)row * 1024 + t * 4;
  f32x4 hv = *(const f32x4*)&hres[base];
  u16x4 dv = *(const u16x4*)&delta[base];
  float x[4];
#pragma unroll
  for (int i = 0; i < 4; i++) x[i] = hv[i] + bf2f(dv[i]);
  float s = x[0] + x[1] + x[2] + x[3];
  float ss = x[0]*x[0] + x[1]*x[1] + x[2]*x[2] + x[3]*x[3];
#pragma unroll
  for (int msk = 32; msk >= 1; msk >>= 1) {
    s  += __shfl_xor(s, msk);
    ss += __shfl_xor(ss, msk);
  }
  __shared__ float rs[4], rq[4];
  const int wv = t >> 6;
  if ((t & 63) == 0) { rs[wv] = s; rq[wv] = ss; }
  __syncthreads();
  s  = rs[0] + rs[1] + rs[2] + rs[3];
  ss = rq[0] + rq[1] + rq[2] + rq[3];
  const float mean = s * (1.0f / 1024.0f);
  const float var  = ss * (1.0f / 1024.0f) - mean * mean;
  const float rstd = rsqrtf(var + 1e-5f);
  f32x4 wv4 = *(const f32x4*)&w[t * 4];
  f32x4 bv4 = *(const f32x4*)&b[t * 4];
  f32x4 yo; u16x4 bo;
#pragma unroll
  for (int i = 0; i < 4; i++) {
    const float y = (x[i] - mean) * rstd * wv4[i] + bv4[i];
    yo[i] = y; bo[i] = f2bf(y);
  }
  *(f32x4*)&hout[base] = yo;
  if (FINAL == 0) *(u16x4*)&bout[base] = bo;
}

// ---------------------------------------------------------------------------
extern "C" void kernel_launch(void* const* d_in, const int* in_sizes, int n_in,
                              void* d_out, int out_size, void* d_ws, size_t ws_size,
                              hipStream_t stream)
{
  (void)in_sizes; (void)n_in; (void)out_size; (void)ws_size;
  const float* x     = (const float*)d_in[0];
  const float* bn_w  = (const float*)d_in[1];
  const float* bn_b  = (const float*)d_in[2];
  const float* qkv_w = (const float*)d_in[3];
  const float* qkv_b = (const float*)d_in[4];
  const float* out_w = (const float*)d_in[5];
  const float* out_b = (const float*)d_in[6];
  const float* ln1_w = (const float*)d_in[7];
  const float* ln1_b = (const float*)d_in[8];
  const float* ln2_w = (const float*)d_in[9];
  const float* ln2_b = (const float*)d_in[10];
  const float* ff1_w = (const float*)d_in[11];
  const float* ff1_b = (const float*)d_in[12];
  const float* ff2_w = (const float*)d_in[13];
  const float* ff2_b = (const float*)d_in[14];

  char* ws = (char*)d_ws;
  float*    h_f32 = (float*)ws;                         // 32 MiB @ 0
  uint16_t* h_bf  = (uint16_t*)(ws + (32u << 20));      // 16 MiB @ 32
  uint16_t* qkvb  = (uint16_t*)(ws + (48u << 20));      // 48 MiB @ 48
  uint16_t* scrA  = (uint16_t*)(ws + (96u << 20));      // 16 MiB @ 96  (112 total)
  float*    outf  = (float*)d_out;                      // fp32 output!

  const int M = 8192;
  dim3 blk(256);

  // bottleneck: h0 = x @ bn_w^T + bn_b  (f32 residual + bf16 copy)
  te_gemm32<<<dim3(8, 64), blk, 0, stream>>>(x, bn_w, bn_b, h_bf, h_f32, M, 1024, 1024);

  for (int l = 0; l < 6; l++) {
    te_gemm_ff<0><<<dim3(24, 64), blk, 0, stream>>>(
        h_bf, 1024, qkv_w + (size_t)l * 3072 * 1024, qkv_b + l * 3072, qkvb, M, 3072, 1024);
    te_attn<<<dim3(8, 16, 16), blk, 0, stream>>>(qkvb);
    te_gemm_ff<0><<<dim3(8, 64), blk, 0, stream>>>(
        qkvb, 3072, out_w + (size_t)l * 1024 * 1024, out_b + l * 1024, scrA, M, 1024, 1024);
    te_ln<0><<<dim3(8192), blk, 0, stream>>>(h_f32, scrA, ln1_w + l * 1024, ln1_b + l * 1024,
                                             h_f32, h_bf);
    te_gemm_ff<2><<<dim3(8, 64), blk, 0, stream>>>(
        h_bf, 1024, ff1_w + (size_t)l * 1024 * 1024, ff1_b + l * 1024, scrA, M, 1024, 1024);
    te_gemm_ff<0><<<dim3(8, 64), blk, 0, stream>>>(
        scrA, 1024, ff2_w + (size_t)l * 1024 * 1024, ff2_b + l * 1024, qkvb, M, 1024, 1024);
    if (l == 5) {
      te_ln<1><<<dim3(8192), blk, 0, stream>>>(h_f32, qkvb, ln2_w + l * 1024, ln2_b + l * 1024,
                                               outf, nullptr);
    } else {
      te_ln<0><<<dim3(8192), blk, 0, stream>>>(h_f32, qkvb, ln2_w + l * 1024, ln2_b + l * 1024,
                                               h_f32, h_bf);
    }
  }
}

// Round 4
// 1840.390 us; speedup vs baseline: 1.0961x; 1.0961x over previous
//
#include <hip/hip_runtime.h>
#include <stdint.h>

#define DEV static __device__ __forceinline__

typedef __attribute__((ext_vector_type(8))) uint16_t u16x8;
typedef __attribute__((ext_vector_type(4))) uint16_t u16x4;
typedef __attribute__((ext_vector_type(4))) float    f32x4;
typedef __attribute__((ext_vector_type(8))) __bf16   bf16x8;

typedef __attribute__((address_space(3))) void lds_void;
typedef __attribute__((address_space(1))) void gbl_void;

DEV float bf2f(uint16_t u){
  union { uint32_t i; float f; } v; v.i = ((uint32_t)u) << 16; return v.f;
}
DEV uint16_t f2bf(float f){        // RNE
  union { float f; uint32_t i; } v; v.f = f;
  uint32_t r = v.i + 0x7FFFu + ((v.i >> 16) & 1u);
  return (uint16_t)(r >> 16);
}
DEV f32x4 mfma16(u16x8 a, u16x8 b, f32x4 c){
  return __builtin_amdgcn_mfma_f32_16x16x32_bf16(
      __builtin_bit_cast(bf16x8, a), __builtin_bit_cast(bf16x8, b), c, 0, 0, 0);
}

// ---------------------------------------------------------------------------
// fp32 -> bf16 elementwise convert, 8 elems/thread. n must be multiple of 2048.
// ---------------------------------------------------------------------------
__global__ __launch_bounds__(256)
void te_cvt(const float* __restrict__ in, uint16_t* __restrict__ out)
{
  const size_t i = ((size_t)blockIdx.x * 256 + threadIdx.x) * 8;
  f32x4 a = *(const f32x4*)(in + i);
  f32x4 b = *(const f32x4*)(in + i + 4);
  u16x8 o;
#pragma unroll
  for (int e = 0; e < 4; e++) {
    o[e]     = __builtin_bit_cast(uint16_t, (__bf16)a[e]);
    o[e + 4] = __builtin_bit_cast(uint16_t, (__bf16)b[e]);
  }
  *(u16x8*)(out + i) = o;
}

// ---------------------------------------------------------------------------
// Pure-bf16 GEMM (m97 structure): out[M,N] = A[M,K](lda) @ W[N,K]^T + bias
// 128x128 tile, BK=64, 256 thr (2x2 waves), dual global_load_lds w=16.
// MODE 0: bias -> bf16.  MODE 1: bias -> bf16 + f32.  MODE 2: bias+GELU -> bf16.
// ---------------------------------------------------------------------------
template<int MODE>
__global__ __launch_bounds__(256)
void te_gemm_bb(const uint16_t* __restrict__ A, int lda,
                const uint16_t* __restrict__ W, const float* __restrict__ bias,
                uint16_t* __restrict__ outB, float* __restrict__ outF,
                int M, int N, int K)
{
  __shared__ uint16_t la[128 * 64];
  __shared__ uint16_t lb[128 * 64];
  const int tid = threadIdx.x;
  const int w = tid >> 6, l = tid & 63;
  const int lr = l & 15, lg = l >> 4;
  const int tm = blockIdx.y * 128, tn = blockIdx.x * 128;
  const int srow = l >> 3, scol = (l & 7) * 8;
  const int wr = (w >> 1) * 64, wc = (w & 1) * 64;

  f32x4 acc[4][4] = {};

  for (int k0 = 0; k0 < K; k0 += 64) {
#pragma unroll
    for (int c = 0; c < 4; c++) {
      const int rb = (c * 4 + w) * 8;
      const uint16_t* ga = A + (size_t)(tm + rb + srow) * lda + (k0 + scol);
      __builtin_amdgcn_global_load_lds((gbl_void*)(uintptr_t)ga,
                                       (lds_void*)(la + rb * 64), 16, 0, 0);
      const uint16_t* gw = W + (size_t)(tn + rb + srow) * K + (k0 + scol);
      __builtin_amdgcn_global_load_lds((gbl_void*)(uintptr_t)gw,
                                       (lds_void*)(lb + rb * 64), 16, 0, 0);
    }
    __syncthreads();
#pragma unroll
    for (int kk = 0; kk < 2; kk++) {
      const int ko = kk * 32 + lg * 8;
      u16x8 af[4], bfr[4];
#pragma unroll
      for (int i = 0; i < 4; i++)
        af[i] = *(const u16x8*)&la[(wr + i * 16 + lr) * 64 + ko];
#pragma unroll
      for (int j = 0; j < 4; j++)
        bfr[j] = *(const u16x8*)&lb[(wc + j * 16 + lr) * 64 + ko];
#pragma unroll
      for (int i = 0; i < 4; i++)
#pragma unroll
        for (int j = 0; j < 4; j++)
          acc[i][j] = mfma16(af[i], bfr[j], acc[i][j]);
    }
    __syncthreads();
  }

  float bv[4];
#pragma unroll
  for (int j = 0; j < 4; j++) bv[j] = bias[tn + wc + j * 16 + lr];
#pragma unroll
  for (int i = 0; i < 4; i++)
#pragma unroll
    for (int j = 0; j < 4; j++)
#pragma unroll
      for (int r = 0; r < 4; r++) {
        const int row = tm + wr + i * 16 + lg * 4 + r;
        const int col = tn + wc + j * 16 + lr;
        float v = acc[i][j][r] + bv[j];
        if (MODE == 2) v = 0.5f * v * (1.0f + erff(v * 0.70710678118654752f));
        const size_t idx = (size_t)row * N + col;
        outB[idx] = f2bf(v);
        if (MODE == 1) outF[idx] = v;
      }
}

// ---------------------------------------------------------------------------
// Fused attention over qkv [B*T, 3072] bf16 (q|k|v, 16 heads x 64).
// Block = (qt, h, b); 4 waves x 16 q-rows; online softmax; alibi bias.
// Output written IN-PLACE into the q region.
// ---------------------------------------------------------------------------
__global__ __launch_bounds__(256)
void te_attn(uint16_t* __restrict__ qkv)
{
  __shared__ uint16_t kl[64 * 72];
  __shared__ uint16_t vt[64 * 72];
  __shared__ uint16_t pl[64 * 72];
  const int tid = threadIdx.x;
  const int w = tid >> 6, l = tid & 63;
  const int lr = l & 15, lg = l >> 4;
  const int qt = blockIdx.x, h = blockIdx.y, b = blockIdx.z;

  u16x8 qf[2];
  {
    const size_t qoff = ((size_t)(b * 512 + qt * 64 + w * 16 + lr)) * 3072 + h * 64 + lg * 8;
    qf[0] = *(const u16x8*)&qkv[qoff];
    qf[1] = *(const u16x8*)&qkv[qoff + 32];
  }
  const float slope = exp2f(-0.5f * (float)(h + 1));
  const float scale = 0.125f;
  const int iBase = qt * 64 + w * 16 + lg * 4;

  float m[4], sd[4];
  f32x4 acc[4] = {};
#pragma unroll
  for (int r = 0; r < 4; r++) { m[r] = -1e30f; sd[r] = 0.0f; }

  for (int jt = 0; jt < 512; jt += 64) {
#pragma unroll
    for (int cc = 0; cc < 2; cc++) {
      const int c = tid + cc * 256;
      const int j = c >> 3, d0 = (c & 7) * 8;
      const size_t rbase = ((size_t)(b * 512 + jt + j)) * 3072 + h * 64 + d0;
      u16x8 kv = *(const u16x8*)&qkv[rbase + 1024];
      *(u16x8*)&kl[j * 72 + d0] = kv;
      u16x8 vv = *(const u16x8*)&qkv[rbase + 2048];
#pragma unroll
      for (int e = 0; e < 8; e++) vt[(d0 + e) * 72 + j] = vv[e];
    }
    __syncthreads();

    f32x4 s[4] = {};
#pragma unroll
    for (int kk = 0; kk < 2; kk++) {
      const int ko = kk * 32 + lg * 8;
#pragma unroll
      for (int n = 0; n < 4; n++) {
        u16x8 kf = *(const u16x8*)&kl[(n * 16 + lr) * 72 + ko];
        s[n] = mfma16(qf[kk], kf, s[n]);
      }
    }
    float mt[4] = { -1e30f, -1e30f, -1e30f, -1e30f };
#pragma unroll
    for (int n = 0; n < 4; n++)
#pragma unroll
      for (int r = 0; r < 4; r++) {
        const int dj = (iBase + r) - (jt + n * 16 + lr);
        const float v = s[n][r] * scale - slope * fabsf((float)dj);
        s[n][r] = v;
        mt[r] = fmaxf(mt[r], v);
      }
#pragma unroll
    for (int r = 0; r < 4; r++)
#pragma unroll
      for (int msk = 1; msk < 16; msk <<= 1)
        mt[r] = fmaxf(mt[r], __shfl_xor(mt[r], msk, 16));
    float fac[4], rsum[4];
#pragma unroll
    for (int r = 0; r < 4; r++) {
      const float mn = fmaxf(m[r], mt[r]);
      fac[r] = __expf(m[r] - mn);
      m[r] = mn;
      rsum[r] = 0.0f;
    }
#pragma unroll
    for (int n = 0; n < 4; n++)
#pragma unroll
      for (int r = 0; r < 4; r++) {
        const float p = __expf(s[n][r] - m[r]);
        s[n][r] = p;
        rsum[r] += p;
      }
#pragma unroll
    for (int r = 0; r < 4; r++) {
#pragma unroll
      for (int msk = 1; msk < 16; msk <<= 1)
        rsum[r] += __shfl_xor(rsum[r], msk, 16);
      sd[r] = sd[r] * fac[r] + rsum[r];
    }
#pragma unroll
    for (int n = 0; n < 4; n++)
#pragma unroll
      for (int r = 0; r < 4; r++) acc[n][r] *= fac[r];

#pragma unroll
    for (int n = 0; n < 4; n++)
#pragma unroll
      for (int r = 0; r < 4; r++)
        pl[(w * 16 + lg * 4 + r) * 72 + n * 16 + lr] = f2bf(s[n][r]);

#pragma unroll
    for (int kk = 0; kk < 2; kk++) {
      const int ko = kk * 32 + lg * 8;
      u16x8 pf = *(const u16x8*)&pl[(w * 16 + lr) * 72 + ko];
#pragma unroll
      for (int n = 0; n < 4; n++) {
        u16x8 vf = *(const u16x8*)&vt[(n * 16 + lr) * 72 + ko];
        acc[n] = mfma16(pf, vf, acc[n]);
      }
    }
    __syncthreads();
  }

#pragma unroll
  for (int n = 0; n < 4; n++)
#pragma unroll
    for (int r = 0; r < 4; r++) {
      const int i = iBase + r;
      const int d = h * 64 + n * 16 + lr;
      qkv[((size_t)(b * 512 + i)) * 3072 + d] = f2bf(acc[n][r] / sd[r]);
    }
}

// ---------------------------------------------------------------------------
// LN: x = hres(f32) + delta(bf16); y = LN(x)*w + b (w,b f32)
// FINAL=0: writes hout (f32, aliases hres) and bout (bf16).
// FINAL=1: writes hout (f32 = d_out) only.
// ---------------------------------------------------------------------------
template<int FINAL>
__global__ __launch_bounds__(256)
void te_ln(const float* __restrict__ hres, const uint16_t* __restrict__ delta,
           const float* __restrict__ w, const float* __restrict__ b,
           float* __restrict__ hout, uint16_t* __restrict__ bout)
{
  const int row = blockIdx.x, t = threadIdx.x;
  const size_t base = (size_t)row * 1024 + t * 4;
  f32x4 hv = *(const f32x4*)&hres[base];
  u16x4 dv = *(const u16x4*)&delta[base];
  float x[4];
#pragma unroll
  for (int i = 0; i < 4; i++) x[i] = hv[i] + bf2f(dv[i]);
  float s = x[0] + x[1] + x[2] + x[3];
  float ss = x[0]*x[0] + x[1]*x[1] + x[2]*x[2] + x[3]*x[3];
#pragma unroll
  for (int msk = 32; msk >= 1; msk >>= 1) {
    s  += __shfl_xor(s, msk);
    ss += __shfl_xor(ss, msk);
  }
  __shared__ float rs[4], rq[4];
  const int wv = t >> 6;
  if ((t & 63) == 0) { rs[wv] = s; rq[wv] = ss; }
  __syncthreads();
  s  = rs[0] + rs[1] + rs[2] + rs[3];
  ss = rq[0] + rq[1] + rq[2] + rq[3];
  const float mean = s * (1.0f / 1024.0f);
  const float var  = ss * (1.0f / 1024.0f) - mean * mean;
  const float rstd = rsqrtf(var + 1e-5f);
  f32x4 wv4 = *(const f32x4*)&w[t * 4];
  f32x4 bv4 = *(const f32x4*)&b[t * 4];
  f32x4 yo; u16x4 bo;
#pragma unroll
  for (int i = 0; i < 4; i++) {
    const float y = (x[i] - mean) * rstd * wv4[i] + bv4[i];
    yo[i] = y; bo[i] = f2bf(y);
  }
  *(f32x4*)&hout[base] = yo;
  if (FINAL == 0) *(u16x4*)&bout[base] = bo;
}

// ---------------------------------------------------------------------------
extern "C" void kernel_launch(void* const* d_in, const int* in_sizes, int n_in,
                              void* d_out, int out_size, void* d_ws, size_t ws_size,
                              hipStream_t stream)
{
  (void)in_sizes; (void)n_in; (void)out_size; (void)ws_size;
  const float* x     = (const float*)d_in[0];
  const float* bn_w  = (const float*)d_in[1];
  const float* bn_b  = (const float*)d_in[2];
  const float* qkv_w = (const float*)d_in[3];
  const float* qkv_b = (const float*)d_in[4];
  const float* out_w = (const float*)d_in[5];
  const float* out_b = (const float*)d_in[6];
  const float* ln1_w = (const float*)d_in[7];
  const float* ln1_b = (const float*)d_in[8];
  const float* ln2_w = (const float*)d_in[9];
  const float* ln2_b = (const float*)d_in[10];
  const float* ff1_w = (const float*)d_in[11];
  const float* ff1_b = (const float*)d_in[12];
  const float* ff2_w = (const float*)d_in[13];
  const float* ff2_b = (const float*)d_in[14];

  char* ws = (char*)d_ws;
  float*    h_f32   = (float*)ws;                         // 32 MiB @ 0
  uint16_t* h_bf    = (uint16_t*)(ws + (32u  << 20));     // 16 MiB @ 32
  uint16_t* qkvb    = (uint16_t*)(ws + (48u  << 20));     // 48 MiB @ 48
  uint16_t* scrA    = (uint16_t*)(ws + (96u  << 20));     // 16 MiB @ 96 (also x_bf)
  uint16_t* qkvw_bf = (uint16_t*)(ws + (112u << 20));     // 36 MiB @ 112
  uint16_t* ff2w_bf = (uint16_t*)(ws + (148u << 20));     // 12 MiB @ 148
  uint16_t* bnw_bf  = (uint16_t*)(ws + (160u << 20));     //  2 MiB @ 160 (162 total)
  // d_out as scratch for weights that die before the final LN writes d_out:
  uint16_t* outw_bf = (uint16_t*)d_out;                   // 12 MiB @ 0
  uint16_t* ff1w_bf = (uint16_t*)((char*)d_out + (12u << 20)); // 12 MiB @ 12
  float*    outf    = (float*)d_out;                      // final fp32 output

  const int M = 8192;
  dim3 blk(256);

  // one-time fp32 -> bf16 conversions (weights + x)
  te_cvt<<<dim3(18874368 / 2048), blk, 0, stream>>>(qkv_w, qkvw_bf);
  te_cvt<<<dim3(6291456  / 2048), blk, 0, stream>>>(out_w, outw_bf);
  te_cvt<<<dim3(6291456  / 2048), blk, 0, stream>>>(ff1_w, ff1w_bf);
  te_cvt<<<dim3(6291456  / 2048), blk, 0, stream>>>(ff2_w, ff2w_bf);
  te_cvt<<<dim3(1048576  / 2048), blk, 0, stream>>>(bn_w,  bnw_bf);
  te_cvt<<<dim3(8388608  / 2048), blk, 0, stream>>>(x,     scrA);

  // bottleneck: h0 = x @ bn_w^T + bn_b  (bf16 + f32 residual)
  te_gemm_bb<1><<<dim3(8, 64), blk, 0, stream>>>(scrA, 1024, bnw_bf, bn_b,
                                                 h_bf, h_f32, M, 1024, 1024);

  for (int l = 0; l < 6; l++) {
    te_gemm_bb<0><<<dim3(24, 64), blk, 0, stream>>>(
        h_bf, 1024, qkvw_bf + (size_t)l * 3072 * 1024, qkv_b + l * 3072,
        qkvb, nullptr, M, 3072, 1024);
    te_attn<<<dim3(8, 16, 16), blk, 0, stream>>>(qkvb);
    te_gemm_bb<0><<<dim3(8, 64), blk, 0, stream>>>(
        qkvb, 3072, outw_bf + (size_t)l * 1024 * 1024, out_b + l * 1024,
        scrA, nullptr, M, 1024, 1024);
    te_ln<0><<<dim3(8192), blk, 0, stream>>>(h_f32, scrA, ln1_w + l * 1024, ln1_b + l * 1024,
                                             h_f32, h_bf);
    te_gemm_bb<2><<<dim3(8, 64), blk, 0, stream>>>(
        h_bf, 1024, ff1w_bf + (size_t)l * 1024 * 1024, ff1_b + l * 1024,
        scrA, nullptr, M, 1024, 1024);
    te_gemm_bb<0><<<dim3(8, 64), blk, 0, stream>>>(
        scrA, 1024, ff2w_bf + (size_t)l * 1024 * 1024, ff2_b + l * 1024,
        qkvb, nullptr, M, 1024, 1024);
    if (l == 5) {
      te_ln<1><<<dim3(8192), blk, 0, stream>>>(h_f32, qkvb, ln2_w + l * 1024, ln2_b + l * 1024,
                                               outf, nullptr);
    } else {
      te_ln<0><<<dim3(8192), blk, 0, stream>>>(h_f32, qkvb, ln2_w + l * 1024, ln2_b + l * 1024,
                                               h_f32, h_bf);
    }
  }
}

// Round 5
// 1713.621 us; speedup vs baseline: 1.1772x; 1.0740x over previous
//
#include <hip/hip_runtime.h>
#include <stdint.h>

#define DEV static __device__ __forceinline__

typedef __attribute__((ext_vector_type(8))) uint16_t u16x8;
typedef __attribute__((ext_vector_type(4))) uint16_t u16x4;
typedef __attribute__((ext_vector_type(4))) float    f32x4;
typedef __attribute__((ext_vector_type(8))) __bf16   bf16x8;

typedef __attribute__((address_space(3))) void lds_void;
typedef __attribute__((address_space(1))) void gbl_void;

DEV float bf2f(uint16_t u){
  union { uint32_t i; float f; } v; v.i = ((uint32_t)u) << 16; return v.f;
}
DEV uint16_t f2bf(float f){ return __builtin_bit_cast(uint16_t, (__bf16)f); }
DEV f32x4 mfma16(u16x8 a, u16x8 b, f32x4 c){
  return __builtin_amdgcn_mfma_f32_16x16x32_bf16(
      __builtin_bit_cast(bf16x8, a), __builtin_bit_cast(bf16x8, b), c, 0, 0, 0);
}

// ---------------------------------------------------------------------------
// fp32 -> bf16 elementwise convert, 8 elems/thread.
// ---------------------------------------------------------------------------
__global__ __launch_bounds__(256)
void te_cvt(const float* __restrict__ in, uint16_t* __restrict__ out)
{
  const size_t i = ((size_t)blockIdx.x * 256 + threadIdx.x) * 8;
  f32x4 a = *(const f32x4*)(in + i);
  f32x4 b = *(const f32x4*)(in + i + 4);
  u16x8 o;
#pragma unroll
  for (int e = 0; e < 4; e++) {
    o[e]     = f2bf(a[e]);
    o[e + 4] = f2bf(b[e]);
  }
  *(u16x8*)(out + i) = o;
}

// ---------------------------------------------------------------------------
// Pure-bf16 GEMM (m97 structure + T2 both-sides swizzle):
// out[M,N] = A[M,K](lda) @ W[N,K]^T + bias
// LDS layout: element (row,d) at row*64 + ((d>>3)^(row&7))*8 + (d&7)
// achieved via pre-swizzled global source (linear global_load_lds dest).
// MODE 0: bias -> bf16.  MODE 1: bias -> bf16 + f32.  MODE 2: bias+GELU -> bf16.
// ---------------------------------------------------------------------------
template<int MODE>
__global__ __launch_bounds__(256)
void te_gemm_bb(const uint16_t* __restrict__ A, int lda,
                const uint16_t* __restrict__ W, const float* __restrict__ bias,
                uint16_t* __restrict__ outB, float* __restrict__ outF,
                int M, int N, int K)
{
  __shared__ uint16_t la[128 * 64];
  __shared__ uint16_t lb[128 * 64];
  const int tid = threadIdx.x;
  const int w = tid >> 6, l = tid & 63;
  const int lr = l & 15, lg = l >> 4;
  const int tm = blockIdx.y * 128, tn = blockIdx.x * 128;
  const int srow = l >> 3;                         // 0..7
  const int scol = ((l & 7) ^ srow) * 8;           // pre-swizzled source chunk
  const int wr = (w >> 1) * 64, wc = (w & 1) * 64;

  f32x4 acc[4][4] = {};

  for (int k0 = 0; k0 < K; k0 += 64) {
#pragma unroll
    for (int c = 0; c < 4; c++) {
      const int rb = (c * 4 + w) * 8;
      const uint16_t* ga = A + (size_t)(tm + rb + srow) * lda + (k0 + scol);
      __builtin_amdgcn_global_load_lds((gbl_void*)(uintptr_t)ga,
                                       (lds_void*)(la + rb * 64), 16, 0, 0);
      const uint16_t* gw = W + (size_t)(tn + rb + srow) * K + (k0 + scol);
      __builtin_amdgcn_global_load_lds((gbl_void*)(uintptr_t)gw,
                                       (lds_void*)(lb + rb * 64), 16, 0, 0);
    }
    __syncthreads();
#pragma unroll
    for (int kk = 0; kk < 2; kk++) {
      u16x8 af[4], bfr[4];
#pragma unroll
      for (int i = 0; i < 4; i++) {
        const int row = wr + i * 16 + lr;
        af[i] = *(const u16x8*)&la[row * 64 + (((kk * 4 + lg) ^ (lr & 7)) << 3)];
      }
#pragma unroll
      for (int j = 0; j < 4; j++) {
        const int row = wc + j * 16 + lr;
        bfr[j] = *(const u16x8*)&lb[row * 64 + (((kk * 4 + lg) ^ (lr & 7)) << 3)];
      }
#pragma unroll
      for (int i = 0; i < 4; i++)
#pragma unroll
        for (int j = 0; j < 4; j++)
          acc[i][j] = mfma16(af[i], bfr[j], acc[i][j]);
    }
    __syncthreads();
  }

  float bv[4];
#pragma unroll
  for (int j = 0; j < 4; j++) bv[j] = bias[tn + wc + j * 16 + lr];
#pragma unroll
  for (int i = 0; i < 4; i++)
#pragma unroll
    for (int j = 0; j < 4; j++)
#pragma unroll
      for (int r = 0; r < 4; r++) {
        const int row = tm + wr + i * 16 + lg * 4 + r;
        const int col = tn + wc + j * 16 + lr;
        float v = acc[i][j][r] + bv[j];
        if (MODE == 2) {
          const float u = 0.7978845608028654f * v * (1.0f + 0.044715f * v * v);
          const float t = 1.0f - 2.0f / (__expf(2.0f * u) + 1.0f);
          v = 0.5f * v * (1.0f + t);
        }
        const size_t idx = (size_t)row * N + col;
        outB[idx] = f2bf(v);
        if (MODE == 1) outF[idx] = v;
      }
}

// ---------------------------------------------------------------------------
// Fused attention over qkv [B*T, 3072] bf16 (q|k|v, 16 heads x 64).
// grid (bh=256, qt=8) so same-(b,h) blocks share an XCD (L2 reuse of K/V).
// Swizzled LDS layouts (XOR 16B chunk by row low bits) -> conflict-free
// staging writes and fragment reads. Output in-place into q region.
// ---------------------------------------------------------------------------
__global__ __launch_bounds__(256)
void te_attn(uint16_t* __restrict__ qkv)
{
  __shared__ uint16_t kl[64 * 64];        // K[j][d] swizzled
  __shared__ uint16_t vt[64 * 64];        // V^T[d][j] swizzled
  __shared__ uint16_t pl[4 * 16 * 64];    // P per wave [q][j] swizzled
  const int tid = threadIdx.x;
  const int w = tid >> 6, l = tid & 63;
  const int lr = l & 15, lg = l >> 4;
  const int bh = blockIdx.x;
  const int qt = blockIdx.y;
  const int h  = bh & 15;
  const int b  = bh >> 4;

  u16x8 qf[2];
  {
    const size_t qoff = ((size_t)(b * 512 + qt * 64 + w * 16 + lr)) * 3072 + h * 64 + lg * 8;
    qf[0] = *(const u16x8*)&qkv[qoff];
    qf[1] = *(const u16x8*)&qkv[qoff + 32];
  }
  const float slope = exp2f(-0.5f * (float)(h + 1));
  const float scale = 0.125f;
  const int iBase = qt * 64 + w * 16 + lg * 4;

  float m[4], sd[4];
  f32x4 acc[4] = {};
#pragma unroll
  for (int r = 0; r < 4; r++) { m[r] = -1e30f; sd[r] = 0.0f; }

  for (int jt = 0; jt < 512; jt += 64) {
    // ---- stage K (vector, swizzled) and V^T (scalar, swizzled) ----
#pragma unroll
    for (int cc = 0; cc < 2; cc++) {
      const int c = tid + cc * 256;
      const int j = c >> 3, d0 = (c & 7) * 8;
      const size_t rbase = ((size_t)(b * 512 + jt + j)) * 3072 + h * 64 + d0;
      u16x8 kv = *(const u16x8*)&qkv[rbase + 1024];
      *(u16x8*)&kl[j * 64 + (((d0 >> 3) ^ (j & 7)) << 3)] = kv;
      u16x8 vv = *(const u16x8*)&qkv[rbase + 2048];
      const int cV = (((j >> 3) ^ (d0 >> 3)) << 3) + (j & 7);
#pragma unroll
      for (int e = 0; e < 8; e++) vt[(d0 + e) * 64 + cV] = vv[e];
    }
    __syncthreads();

    // ---- S = Q K^T ----
    f32x4 s[4] = {};
#pragma unroll
    for (int kk = 0; kk < 2; kk++) {
#pragma unroll
      for (int n = 0; n < 4; n++) {
        const int row = n * 16 + lr;
        u16x8 kf = *(const u16x8*)&kl[row * 64 + (((kk * 4 + lg) ^ (lr & 7)) << 3)];
        s[n] = mfma16(qf[kk], kf, s[n]);
      }
    }
    // ---- scale + alibi, online softmax ----
    float mt[4] = { -1e30f, -1e30f, -1e30f, -1e30f };
#pragma unroll
    for (int n = 0; n < 4; n++)
#pragma unroll
      for (int r = 0; r < 4; r++) {
        const int dj = (iBase + r) - (jt + n * 16 + lr);
        const float v = s[n][r] * scale - slope * fabsf((float)dj);
        s[n][r] = v;
        mt[r] = fmaxf(mt[r], v);
      }
#pragma unroll
    for (int r = 0; r < 4; r++)
#pragma unroll
      for (int msk = 1; msk < 16; msk <<= 1)
        mt[r] = fmaxf(mt[r], __shfl_xor(mt[r], msk, 16));
    float fac[4], rsum[4];
#pragma unroll
    for (int r = 0; r < 4; r++) {
      const float mn = fmaxf(m[r], mt[r]);
      fac[r] = __expf(m[r] - mn);
      m[r] = mn;
      rsum[r] = 0.0f;
    }
#pragma unroll
    for (int n = 0; n < 4; n++)
#pragma unroll
      for (int r = 0; r < 4; r++) {
        const float p = __expf(s[n][r] - m[r]);
        s[n][r] = p;
        rsum[r] += p;
      }
#pragma unroll
    for (int r = 0; r < 4; r++) {
#pragma unroll
      for (int msk = 1; msk < 16; msk <<= 1)
        rsum[r] += __shfl_xor(rsum[r], msk, 16);
      sd[r] = sd[r] * fac[r] + rsum[r];
    }
#pragma unroll
    for (int n = 0; n < 4; n++)
#pragma unroll
      for (int r = 0; r < 4; r++) acc[n][r] *= fac[r];

    // ---- P -> LDS (swizzled), then PV ----
#pragma unroll
    for (int n = 0; n < 4; n++)
#pragma unroll
      for (int r = 0; r < 4; r++) {
        const int q = lg * 4 + r;
        const int chunk = ((2 * n + (lr >> 3)) ^ (q & 7)) & 7;
        pl[w * 1024 + q * 64 + chunk * 8 + (lr & 7)] = f2bf(s[n][r]);
      }

#pragma unroll
    for (int kk = 0; kk < 2; kk++) {
      u16x8 pf = *(const u16x8*)&pl[w * 1024 + lr * 64 + (((kk * 4 + lg) ^ (lr & 7)) << 3)];
#pragma unroll
      for (int n = 0; n < 4; n++) {
        const int row = n * 16 + lr;
        u16x8 vf = *(const u16x8*)&vt[row * 64 + ((((kk * 4 + lg) ^ (2 * n + (lr >> 3))) & 7) << 3)];
        acc[n] = mfma16(pf, vf, acc[n]);
      }
    }
    __syncthreads();
  }

#pragma unroll
  for (int n = 0; n < 4; n++)
#pragma unroll
    for (int r = 0; r < 4; r++) {
      const int i = iBase + r;
      const int d = h * 64 + n * 16 + lr;
      qkv[((size_t)(b * 512 + i)) * 3072 + d] = f2bf(acc[n][r] / sd[r]);
    }
}

// ---------------------------------------------------------------------------
// LN: x = hres(f32) + delta(bf16); y = LN(x)*w + b (w,b f32)
// FINAL=0: writes hout (f32, aliases hres) and bout (bf16).
// FINAL=1: writes hout (f32 = d_out) only.
// ---------------------------------------------------------------------------
template<int FINAL>
__global__ __launch_bounds__(256)
void te_ln(const float* __restrict__ hres, const uint16_t* __restrict__ delta,
           const float* __restrict__ w, const float* __restrict__ b,
           float* __restrict__ hout, uint16_t* __restrict__ bout)
{
  const int row = blockIdx.x, t = threadIdx.x;
  const size_t base = (size_t)row * 1024 + t * 4;
  f32x4 hv = *(const f32x4*)&hres[base];
  u16x4 dv = *(const u16x4*)&delta[base];
  float x[4];
#pragma unroll
  for (int i = 0; i < 4; i++) x[i] = hv[i] + bf2f(dv[i]);
  float s = x[0] + x[1] + x[2] + x[3];
  float ss = x[0]*x[0] + x[1]*x[1] + x[2]*x[2] + x[3]*x[3];
#pragma unroll
  for (int msk = 32; msk >= 1; msk >>= 1) {
    s  += __shfl_xor(s, msk);
    ss += __shfl_xor(ss, msk);
  }
  __shared__ float rs[4], rq[4];
  const int wv = t >> 6;
  if ((t & 63) == 0) { rs[wv] = s; rq[wv] = ss; }
  __syncthreads();
  s  = rs[0] + rs[1] + rs[2] + rs[3];
  ss = rq[0] + rq[1] + rq[2] + rq[3];
  const float mean = s * (1.0f / 1024.0f);
  const float var  = ss * (1.0f / 1024.0f) - mean * mean;
  const float rstd = rsqrtf(var + 1e-5f);
  f32x4 wv4 = *(const f32x4*)&w[t * 4];
  f32x4 bv4 = *(const f32x4*)&b[t * 4];
  f32x4 yo; u16x4 bo;
#pragma unroll
  for (int i = 0; i < 4; i++) {
    const float y = (x[i] - mean) * rstd * wv4[i] + bv4[i];
    yo[i] = y; bo[i] = f2bf(y);
  }
  *(f32x4*)&hout[base] = yo;
  if (FINAL == 0) *(u16x4*)&bout[base] = bo;
}

// ---------------------------------------------------------------------------
extern "C" void kernel_launch(void* const* d_in, const int* in_sizes, int n_in,
                              void* d_out, int out_size, void* d_ws, size_t ws_size,
                              hipStream_t stream)
{
  (void)in_sizes; (void)n_in; (void)out_size; (void)ws_size;
  const float* x     = (const float*)d_in[0];
  const float* bn_w  = (const float*)d_in[1];
  const float* bn_b  = (const float*)d_in[2];
  const float* qkv_w = (const float*)d_in[3];
  const float* qkv_b = (const float*)d_in[4];
  const float* out_w = (const float*)d_in[5];
  const float* out_b = (const float*)d_in[6];
  const float* ln1_w = (const float*)d_in[7];
  const float* ln1_b = (const float*)d_in[8];
  const float* ln2_w = (const float*)d_in[9];
  const float* ln2_b = (const float*)d_in[10];
  const float* ff1_w = (const float*)d_in[11];
  const float* ff1_b = (const float*)d_in[12];
  const float* ff2_w = (const float*)d_in[13];
  const float* ff2_b = (const float*)d_in[14];

  char* ws = (char*)d_ws;
  float*    h_f32   = (float*)ws;                         // 32 MiB @ 0
  uint16_t* h_bf    = (uint16_t*)(ws + (32u  << 20));     // 16 MiB @ 32
  uint16_t* qkvb    = (uint16_t*)(ws + (48u  << 20));     // 48 MiB @ 48
  uint16_t* scrA    = (uint16_t*)(ws + (96u  << 20));     // 16 MiB @ 96 (also x_bf)
  uint16_t* qkvw_bf = (uint16_t*)(ws + (112u << 20));     // 36 MiB @ 112
  uint16_t* ff2w_bf = (uint16_t*)(ws + (148u << 20));     // 12 MiB @ 148
  uint16_t* bnw_bf  = (uint16_t*)(ws + (160u << 20));     //  2 MiB @ 160 (162 total)
  // d_out as scratch for weights that die before the final LN writes d_out:
  uint16_t* outw_bf = (uint16_t*)d_out;                   // 12 MiB @ 0
  uint16_t* ff1w_bf = (uint16_t*)((char*)d_out + (12u << 20)); // 12 MiB @ 12
  float*    outf    = (float*)d_out;                      // final fp32 output

  const int M = 8192;
  dim3 blk(256);

  // one-time fp32 -> bf16 conversions (weights + x)
  te_cvt<<<dim3(18874368 / 2048), blk, 0, stream>>>(qkv_w, qkvw_bf);
  te_cvt<<<dim3(6291456  / 2048), blk, 0, stream>>>(out_w, outw_bf);
  te_cvt<<<dim3(6291456  / 2048), blk, 0, stream>>>(ff1_w, ff1w_bf);
  te_cvt<<<dim3(6291456  / 2048), blk, 0, stream>>>(ff2_w, ff2w_bf);
  te_cvt<<<dim3(1048576  / 2048), blk, 0, stream>>>(bn_w,  bnw_bf);
  te_cvt<<<dim3(8388608  / 2048), blk, 0, stream>>>(x,     scrA);

  // bottleneck: h0 = x @ bn_w^T + bn_b  (bf16 + f32 residual)
  te_gemm_bb<1><<<dim3(8, 64), blk, 0, stream>>>(scrA, 1024, bnw_bf, bn_b,
                                                 h_bf, h_f32, M, 1024, 1024);

  for (int l = 0; l < 6; l++) {
    te_gemm_bb<0><<<dim3(24, 64), blk, 0, stream>>>(
        h_bf, 1024, qkvw_bf + (size_t)l * 3072 * 1024, qkv_b + l * 3072,
        qkvb, nullptr, M, 3072, 1024);
    te_attn<<<dim3(256, 8), blk, 0, stream>>>(qkvb);
    te_gemm_bb<0><<<dim3(8, 64), blk, 0, stream>>>(
        qkvb, 3072, outw_bf + (size_t)l * 1024 * 1024, out_b + l * 1024,
        scrA, nullptr, M, 1024, 1024);
    te_ln<0><<<dim3(8192), blk, 0, stream>>>(h_f32, scrA, ln1_w + l * 1024, ln1_b + l * 1024,
                                             h_f32, h_bf);
    te_gemm_bb<2><<<dim3(8, 64), blk, 0, stream>>>(
        h_bf, 1024, ff1w_bf + (size_t)l * 1024 * 1024, ff1_b + l * 1024,
        scrA, nullptr, M, 1024, 1024);
    te_gemm_bb<0><<<dim3(8, 64), blk, 0, stream>>>(
        scrA, 1024, ff2w_bf + (size_t)l * 1024 * 1024, ff2_b + l * 1024,
        qkvb, nullptr, M, 1024, 1024);
    if (l == 5) {
      te_ln<1><<<dim3(8192), blk, 0, stream>>>(h_f32, qkvb, ln2_w + l * 1024, ln2_b + l * 1024,
                                               outf, nullptr);
    } else {
      te_ln<0><<<dim3(8192), blk, 0, stream>>>(h_f32, qkvb, ln2_w + l * 1024, ln2_b + l * 1024,
                                               h_f32, h_bf);
    }
  }
}

// Round 6
// 1567.029 us; speedup vs baseline: 1.2873x; 1.0935x over previous
//
#include <hip/hip_runtime.h>
#include <stdint.h>

#define DEV static __device__ __forceinline__

typedef __attribute__((ext_vector_type(8))) uint16_t u16x8;
typedef __attribute__((ext_vector_type(4))) uint16_t u16x4;
typedef __attribute__((ext_vector_type(4))) uint32_t u32x4;
typedef __attribute__((ext_vector_type(4))) float    f32x4;
typedef __attribute__((ext_vector_type(8))) __bf16   bf16x8;

typedef __attribute__((address_space(3))) void lds_void;
typedef __attribute__((address_space(1))) void gbl_void;

DEV float bf2f(uint16_t u){
  union { uint32_t i; float f; } v; v.i = ((uint32_t)u) << 16; return v.f;
}
DEV uint16_t f2bf(float f){ return __builtin_bit_cast(uint16_t, (__bf16)f); }
DEV f32x4 mfma16(u16x8 a, u16x8 b, f32x4 c){
  return __builtin_amdgcn_mfma_f32_16x16x32_bf16(
      __builtin_bit_cast(bf16x8, a), __builtin_bit_cast(bf16x8, b), c, 0, 0, 0);
}
DEV uint32_t cvt_pk_bf16(float lo, float hi){
  uint32_t r;
  asm("v_cvt_pk_bf16_f32 %0, %1, %2" : "=v"(r) : "v"(lo), "v"(hi));
  return r;
}

// ---------------------------------------------------------------------------
// fp32 -> bf16 elementwise convert, 8 elems/thread.
// ---------------------------------------------------------------------------
__global__ __launch_bounds__(256)
void te_cvt(const float* __restrict__ in, uint16_t* __restrict__ out)
{
  const size_t i = ((size_t)blockIdx.x * 256 + threadIdx.x) * 8;
  f32x4 a = *(const f32x4*)(in + i);
  f32x4 b = *(const f32x4*)(in + i + 4);
  u16x8 o;
#pragma unroll
  for (int e = 0; e < 4; e++) {
    o[e]     = f2bf(a[e]);
    o[e + 4] = f2bf(b[e]);
  }
  *(u16x8*)(out + i) = o;
}

// ---------------------------------------------------------------------------
// Pure-bf16 GEMM (m97 structure + T2 both-sides swizzle):
// out[M,N] = A[M,K](lda) @ W[N,K]^T + bias
// MODE 0: bias -> bf16.  MODE 1: bias -> bf16 + f32.  MODE 2: bias+GELU -> bf16.
// ---------------------------------------------------------------------------
template<int MODE>
__global__ __launch_bounds__(256)
void te_gemm_bb(const uint16_t* __restrict__ A, int lda,
                const uint16_t* __restrict__ W, const float* __restrict__ bias,
                uint16_t* __restrict__ outB, float* __restrict__ outF,
                int M, int N, int K)
{
  __shared__ uint16_t la[128 * 64];
  __shared__ uint16_t lb[128 * 64];
  const int tid = threadIdx.x;
  const int w = tid >> 6, l = tid & 63;
  const int lr = l & 15, lg = l >> 4;
  const int tm = blockIdx.y * 128, tn = blockIdx.x * 128;
  const int srow = l >> 3;
  const int scol = ((l & 7) ^ srow) * 8;           // pre-swizzled source chunk
  const int wr = (w >> 1) * 64, wc = (w & 1) * 64;

  f32x4 acc[4][4] = {};

  for (int k0 = 0; k0 < K; k0 += 64) {
#pragma unroll
    for (int c = 0; c < 4; c++) {
      const int rb = (c * 4 + w) * 8;
      const uint16_t* ga = A + (size_t)(tm + rb + srow) * lda + (k0 + scol);
      __builtin_amdgcn_global_load_lds((gbl_void*)(uintptr_t)ga,
                                       (lds_void*)(la + rb * 64), 16, 0, 0);
      const uint16_t* gw = W + (size_t)(tn + rb + srow) * K + (k0 + scol);
      __builtin_amdgcn_global_load_lds((gbl_void*)(uintptr_t)gw,
                                       (lds_void*)(lb + rb * 64), 16, 0, 0);
    }
    __syncthreads();
#pragma unroll
    for (int kk = 0; kk < 2; kk++) {
      u16x8 af[4], bfr[4];
#pragma unroll
      for (int i = 0; i < 4; i++) {
        const int row = wr + i * 16 + lr;
        af[i] = *(const u16x8*)&la[row * 64 + (((kk * 4 + lg) ^ (lr & 7)) << 3)];
      }
#pragma unroll
      for (int j = 0; j < 4; j++) {
        const int row = wc + j * 16 + lr;
        bfr[j] = *(const u16x8*)&lb[row * 64 + (((kk * 4 + lg) ^ (lr & 7)) << 3)];
      }
      __builtin_amdgcn_s_setprio(1);
#pragma unroll
      for (int i = 0; i < 4; i++)
#pragma unroll
        for (int j = 0; j < 4; j++)
          acc[i][j] = mfma16(af[i], bfr[j], acc[i][j]);
      __builtin_amdgcn_s_setprio(0);
    }
    __syncthreads();
  }

  float bv[4];
#pragma unroll
  for (int j = 0; j < 4; j++) bv[j] = bias[tn + wc + j * 16 + lr];
#pragma unroll
  for (int i = 0; i < 4; i++)
#pragma unroll
    for (int j = 0; j < 4; j++)
#pragma unroll
      for (int r = 0; r < 4; r++) {
        const int row = tm + wr + i * 16 + lg * 4 + r;
        const int col = tn + wc + j * 16 + lr;
        float v = acc[i][j][r] + bv[j];
        if (MODE == 2) {
          const float u = 0.7978845608028654f * v * (1.0f + 0.044715f * v * v);
          const float t = 1.0f - 2.0f / (__expf(2.0f * u) + 1.0f);
          v = 0.5f * v * (1.0f + t);
        }
        const size_t idx = (size_t)row * N + col;
        outB[idx] = f2bf(v);
        if (MODE == 1) outF[idx] = v;
      }
}

// ---------------------------------------------------------------------------
// Fused attention v2: swapped QK^T (S^T layout, lane-local row softmax),
// exp2-domain, exact defer-max (diag-first tile order), in-register P
// redistribution (cvt_pk + shfl), async-stage split. In-place q output.
// qkv [B*T, 3072] bf16; grid (bh=256, qt=8).
// ---------------------------------------------------------------------------
__global__ __launch_bounds__(256)
void te_attn(uint16_t* __restrict__ qkv)
{
  __shared__ uint16_t kl[64 * 64];   // K[j][d] swizzled chunks
  __shared__ uint16_t vt[64 * 64];   // V^T[d][j] swizzled chunks
  const int tid = threadIdx.x;
  const int w = tid >> 6, l = tid & 63;
  const int lr = l & 15, lg = l >> 4;
  const int bh = blockIdx.x, qt = blockIdx.y;
  const int h = bh & 15, b = bh >> 4;

  // Q fragment (B-operand): lane holds Q[i=iQ][k = kk*32 + lg*8 + e]
  const int iQ = qt * 64 + w * 16 + lr;
  u16x8 qf[2];
  {
    const size_t qoff = ((size_t)(b * 512 + iQ)) * 3072 + h * 64 + lg * 8;
    qf[0] = *(const u16x8*)&qkv[qoff];
    qf[1] = *(const u16x8*)&qkv[qoff + 32];
  }
  const float LOG2E  = 1.4426950408889634f;
  const float scl2e  = 0.125f * LOG2E;
  const float slope2e = exp2f(-0.5f * (float)(h + 1)) * LOG2E;

  const int sjb = tid >> 3;           // 0..31 (j within half-tile)
  const int sd0 = (tid & 7) * 8;      // d chunk start

  float mR = -1e30f, sdq = 0.0f;
  f32x4 acc[4] = {};

  // prologue: load diagonal tile into regs
  u16x8 kreg[2], vreg[2];
  {
    const int jt0 = (qt & 7) * 64;
#pragma unroll
    for (int cc = 0; cc < 2; cc++) {
      const int j = sjb + cc * 32;
      const size_t rbase = ((size_t)(b * 512 + jt0 + j)) * 3072 + h * 64 + sd0;
      kreg[cc] = *(const u16x8*)&qkv[rbase + 1024];
      vreg[cc] = *(const u16x8*)&qkv[rbase + 2048];
    }
  }

  for (int step = 0; step < 8; step++) {
    const int jt = ((qt + step) & 7) * 64;
    // ---- write staged regs to LDS ----
#pragma unroll
    for (int cc = 0; cc < 2; cc++) {
      const int j = sjb + cc * 32;
      *(u16x8*)&kl[j * 64 + (((sd0 >> 3) ^ (j & 7)) << 3)] = kreg[cc];
      const int cV = (((j >> 3) ^ (sd0 >> 3)) << 3) + (j & 7);
#pragma unroll
      for (int e = 0; e < 8; e++) vt[(sd0 + e) * 64 + cV] = vreg[cc][e];
    }
    __syncthreads();
    // ---- issue next tile's global loads (hidden under compute) ----
    if (step < 7) {
      const int jtn = ((qt + step + 1) & 7) * 64;
#pragma unroll
      for (int cc = 0; cc < 2; cc++) {
        const int j = sjb + cc * 32;
        const size_t rbase = ((size_t)(b * 512 + jtn + j)) * 3072 + h * 64 + sd0;
        kreg[cc] = *(const u16x8*)&qkv[rbase + 1024];
        vreg[cc] = *(const u16x8*)&qkv[rbase + 2048];
      }
    }

    // ---- S^T = mfma(K, Q): s[n][r] = S[q=iQ][j = jt + n*16 + lg*4 + r] ----
    f32x4 s[4] = {};
#pragma unroll
    for (int kk = 0; kk < 2; kk++) {
      u16x8 kf[4];
#pragma unroll
      for (int n = 0; n < 4; n++) {
        const int row = n * 16 + lr;
        kf[n] = *(const u16x8*)&kl[row * 64 + (((kk * 4 + lg) ^ (lr & 7)) << 3)];
      }
      __builtin_amdgcn_s_setprio(1);
#pragma unroll
      for (int n = 0; n < 4; n++)
        s[n] = mfma16(kf[n], qf[kk], s[n]);
      __builtin_amdgcn_s_setprio(0);
    }

    // ---- alibi bias + lane-local row max ----
    const float f0 = (float)(iQ - jt - lg * 4);
    float mt = -1e30f;
#pragma unroll
    for (int n = 0; n < 4; n++) {
      const float fj = f0 - (float)(n * 16);
#pragma unroll
      for (int r = 0; r < 4; r++) {
        const float v = fmaf(s[n][r], scl2e, -slope2e * fabsf(fj - (float)r));
        s[n][r] = v;
        mt = fmaxf(mt, v);
      }
    }
    mt = fmaxf(mt, __shfl_xor(mt, 16));
    mt = fmaxf(mt, __shfl_xor(mt, 32));

    // ---- exact defer-max: rescale only when max grows ----
    if (!__all(mt <= mR)) {
      const float mN = fmaxf(mR, mt);
      const float fq = exp2f(mR - mN);
      mR = mN;
      sdq *= fq;
      float fA[4];
#pragma unroll
      for (int r = 0; r < 4; r++) fA[r] = __shfl(fq, lg * 4 + r);
#pragma unroll
      for (int n = 0; n < 4; n++)
#pragma unroll
        for (int r = 0; r < 4; r++) acc[n][r] *= fA[r];
    }

    // ---- exp2 + row sum ----
    float rs = 0.0f;
#pragma unroll
    for (int n = 0; n < 4; n++)
#pragma unroll
      for (int r = 0; r < 4; r++) {
        const float p = exp2f(s[n][r] - mR);
        s[n][r] = p;
        rs += p;
      }
    rs += __shfl_xor(rs, 16);
    rs += __shfl_xor(rs, 32);
    sdq += rs;

    // ---- pack P pairs (j = n*16 + lg*4 + 2u,2u+1) ----
    uint32_t P2[4][2];
#pragma unroll
    for (int n = 0; n < 4; n++) {
      P2[n][0] = cvt_pk_bf16(s[n][0], s[n][1]);
      P2[n][1] = cvt_pk_bf16(s[n][2], s[n][3]);
    }

    // ---- redistribute to A-frag layout + PV ----
#pragma unroll
    for (int kk = 0; kk < 2; kk++) {
      uint32_t pw[4];
#pragma unroll
      for (int t = 0; t < 4; t++) {
        const int srcLane = lr + 16 * ((lg & 1) * 2 + (t >> 1));
        const uint32_t xa = __shfl(P2[2 * kk + 0][t & 1], srcLane);
        const uint32_t xb = __shfl(P2[2 * kk + 1][t & 1], srcLane);
        pw[t] = (lg >> 1) ? xb : xa;
      }
      u32x4 pv4 = { pw[0], pw[1], pw[2], pw[3] };
      u16x8 pf = __builtin_bit_cast(u16x8, pv4);
      u16x8 vf[4];
#pragma unroll
      for (int n = 0; n < 4; n++) {
        const int row = n * 16 + lr;
        vf[n] = *(const u16x8*)&vt[row * 64 + ((((kk * 4 + lg) ^ (2 * n + (lr >> 3))) & 7) << 3)];
      }
      __builtin_amdgcn_s_setprio(1);
#pragma unroll
      for (int n = 0; n < 4; n++)
        acc[n] = mfma16(pf, vf[n], acc[n]);
      __builtin_amdgcn_s_setprio(0);
    }
    __syncthreads();
  }

  // ---- epilogue: O[i = qt*64 + w*16 + lg*4 + r][d = h*64 + n*16 + lr] ----
  float sdA[4];
#pragma unroll
  for (int r = 0; r < 4; r++) sdA[r] = 1.0f / __shfl(sdq, lg * 4 + r);
#pragma unroll
  for (int n = 0; n < 4; n++)
#pragma unroll
    for (int r = 0; r < 4; r++) {
      const int i = qt * 64 + w * 16 + lg * 4 + r;
      const int d = h * 64 + n * 16 + lr;
      qkv[((size_t)(b * 512 + i)) * 3072 + d] = f2bf(acc[n][r] * sdA[r]);
    }
}

// ---------------------------------------------------------------------------
// LN: x = hres(f32) + delta(bf16); y = LN(x)*w + b (w,b f32)
// FINAL=0: writes hout (f32, aliases hres) and bout (bf16).
// FINAL=1: writes hout (f32 = d_out) only.
// ---------------------------------------------------------------------------
template<int FINAL>
__global__ __launch_bounds__(256)
void te_ln(const float* __restrict__ hres, const uint16_t* __restrict__ delta,
           const float* __restrict__ w, const float* __restrict__ b,
           float* __restrict__ hout, uint16_t* __restrict__ bout)
{
  const int row = blockIdx.x, t = threadIdx.x;
  const size_t base = (size_t)row * 1024 + t * 4;
  f32x4 hv = *(const f32x4*)&hres[base];
  u16x4 dv = *(const u16x4*)&delta[base];
  float x[4];
#pragma unroll
  for (int i = 0; i < 4; i++) x[i] = hv[i] + bf2f(dv[i]);
  float s = x[0] + x[1] + x[2] + x[3];
  float ss = x[0]*x[0] + x[1]*x[1] + x[2]*x[2] + x[3]*x[3];
#pragma unroll
  for (int msk = 32; msk >= 1; msk >>= 1) {
    s  += __shfl_xor(s, msk);
    ss += __shfl_xor(ss, msk);
  }
  __shared__ float rs[4], rq[4];
  const int wv = t >> 6;
  if ((t & 63) == 0) { rs[wv] = s; rq[wv] = ss; }
  __syncthreads();
  s  = rs[0] + rs[1] + rs[2] + rs[3];
  ss = rq[0] + rq[1] + rq[2] + rq[3];
  const float mean = s * (1.0f / 1024.0f);
  const float var  = ss * (1.0f / 1024.0f) - mean * mean;
  const float rstd = rsqrtf(var + 1e-5f);
  f32x4 wv4 = *(const f32x4*)&w[t * 4];
  f32x4 bv4 = *(const f32x4*)&b[t * 4];
  f32x4 yo; u16x4 bo;
#pragma unroll
  for (int i = 0; i < 4; i++) {
    const float y = (x[i] - mean) * rstd * wv4[i] + bv4[i];
    yo[i] = y; bo[i] = f2bf(y);
  }
  *(f32x4*)&hout[base] = yo;
  if (FINAL == 0) *(u16x4*)&bout[base] = bo;
}

// ---------------------------------------------------------------------------
extern "C" void kernel_launch(void* const* d_in, const int* in_sizes, int n_in,
                              void* d_out, int out_size, void* d_ws, size_t ws_size,
                              hipStream_t stream)
{
  (void)in_sizes; (void)n_in; (void)out_size; (void)ws_size;
  const float* x     = (const float*)d_in[0];
  const float* bn_w  = (const float*)d_in[1];
  const float* bn_b  = (const float*)d_in[2];
  const float* qkv_w = (const float*)d_in[3];
  const float* qkv_b = (const float*)d_in[4];
  const float* out_w = (const float*)d_in[5];
  const float* out_b = (const float*)d_in[6];
  const float* ln1_w = (const float*)d_in[7];
  const float* ln1_b = (const float*)d_in[8];
  const float* ln2_w = (const float*)d_in[9];
  const float* ln2_b = (const float*)d_in[10];
  const float* ff1_w = (const float*)d_in[11];
  const float* ff1_b = (const float*)d_in[12];
  const float* ff2_w = (const float*)d_in[13];
  const float* ff2_b = (const float*)d_in[14];

  char* ws = (char*)d_ws;
  float*    h_f32   = (float*)ws;                         // 32 MiB @ 0
  uint16_t* h_bf    = (uint16_t*)(ws + (32u  << 20));     // 16 MiB @ 32
  uint16_t* qkvb    = (uint16_t*)(ws + (48u  << 20));     // 48 MiB @ 48
  uint16_t* scrA    = (uint16_t*)(ws + (96u  << 20));     // 16 MiB @ 96 (also x_bf)
  uint16_t* qkvw_bf = (uint16_t*)(ws + (112u << 20));     // 36 MiB @ 112
  uint16_t* ff2w_bf = (uint16_t*)(ws + (148u << 20));     // 12 MiB @ 148
  uint16_t* bnw_bf  = (uint16_t*)(ws + (160u << 20));     //  2 MiB @ 160 (162 total)
  // d_out as scratch for weights that die before the final LN writes d_out:
  uint16_t* outw_bf = (uint16_t*)d_out;                   // 12 MiB @ 0
  uint16_t* ff1w_bf = (uint16_t*)((char*)d_out + (12u << 20)); // 12 MiB @ 12
  float*    outf    = (float*)d_out;                      // final fp32 output

  const int M = 8192;
  dim3 blk(256);

  // one-time fp32 -> bf16 conversions (weights + x)
  te_cvt<<<dim3(18874368 / 2048), blk, 0, stream>>>(qkv_w, qkvw_bf);
  te_cvt<<<dim3(6291456  / 2048), blk, 0, stream>>>(out_w, outw_bf);
  te_cvt<<<dim3(6291456  / 2048), blk, 0, stream>>>(ff1_w, ff1w_bf);
  te_cvt<<<dim3(6291456  / 2048), blk, 0, stream>>>(ff2_w, ff2w_bf);
  te_cvt<<<dim3(1048576  / 2048), blk, 0, stream>>>(bn_w,  bnw_bf);
  te_cvt<<<dim3(8388608  / 2048), blk, 0, stream>>>(x,     scrA);

  // bottleneck: h0 = x @ bn_w^T + bn_b  (bf16 + f32 residual)
  te_gemm_bb<1><<<dim3(8, 64), blk, 0, stream>>>(scrA, 1024, bnw_bf, bn_b,
                                                 h_bf, h_f32, M, 1024, 1024);

  for (int l = 0; l < 6; l++) {
    te_gemm_bb<0><<<dim3(24, 64), blk, 0, stream>>>(
        h_bf, 1024, qkvw_bf + (size_t)l * 3072 * 1024, qkv_b + l * 3072,
        qkvb, nullptr, M, 3072, 1024);
    te_attn<<<dim3(256, 8), blk, 0, stream>>>(qkvb);
    te_gemm_bb<0><<<dim3(8, 64), blk, 0, stream>>>(
        qkvb, 3072, outw_bf + (size_t)l * 1024 * 1024, out_b + l * 1024,
        scrA, nullptr, M, 1024, 1024);
    te_ln<0><<<dim3(8192), blk, 0, stream>>>(h_f32, scrA, ln1_w + l * 1024, ln1_b + l * 1024,
                                             h_f32, h_bf);
    te_gemm_bb<2><<<dim3(8, 64), blk, 0, stream>>>(
        h_bf, 1024, ff1w_bf + (size_t)l * 1024 * 1024, ff1_b + l * 1024,
        scrA, nullptr, M, 1024, 1024);
    te_gemm_bb<0><<<dim3(8, 64), blk, 0, stream>>>(
        scrA, 1024, ff2w_bf + (size_t)l * 1024 * 1024, ff2_b + l * 1024,
        qkvb, nullptr, M, 1024, 1024);
    if (l == 5) {
      te_ln<1><<<dim3(8192), blk, 0, stream>>>(h_f32, qkvb, ln2_w + l * 1024, ln2_b + l * 1024,
                                               outf, nullptr);
    } else {
      te_ln<0><<<dim3(8192), blk, 0, stream>>>(h_f32, qkvb, ln2_w + l * 1024, ln2_b + l * 1024,
                                               h_f32, h_bf);
    }
  }
}

// Round 7
// 1473.817 us; speedup vs baseline: 1.3687x; 1.0632x over previous
//
#include <hip/hip_runtime.h>
#include <stdint.h>

#define DEV static __device__ __forceinline__

typedef __attribute__((ext_vector_type(8))) uint16_t u16x8;
typedef __attribute__((ext_vector_type(4))) uint16_t u16x4;
typedef __attribute__((ext_vector_type(4))) uint32_t u32x4;
typedef __attribute__((ext_vector_type(4))) float    f32x4;
typedef __attribute__((ext_vector_type(8))) __bf16   bf16x8;

typedef __attribute__((address_space(3))) void lds_void;
typedef __attribute__((address_space(1))) void gbl_void;

DEV float bf2f(uint16_t u){
  union { uint32_t i; float f; } v; v.i = ((uint32_t)u) << 16; return v.f;
}
DEV uint16_t f2bf(float f){ return __builtin_bit_cast(uint16_t, (__bf16)f); }
DEV f32x4 mfma16(u16x8 a, u16x8 b, f32x4 c){
  return __builtin_amdgcn_mfma_f32_16x16x32_bf16(
      __builtin_bit_cast(bf16x8, a), __builtin_bit_cast(bf16x8, b), c, 0, 0, 0);
}
DEV uint32_t cvt_pk_bf16(float lo, float hi){
  uint32_t r;
  asm("v_cvt_pk_bf16_f32 %0, %1, %2" : "=v"(r) : "v"(lo), "v"(hi));
  return r;
}

// ---------------------------------------------------------------------------
// fp32 -> bf16 elementwise convert, 8 elems/thread.
// ---------------------------------------------------------------------------
__global__ __launch_bounds__(256)
void te_cvt(const float* __restrict__ in, uint16_t* __restrict__ out)
{
  const size_t i = ((size_t)blockIdx.x * 256 + threadIdx.x) * 8;
  f32x4 a = *(const f32x4*)(in + i);
  f32x4 b = *(const f32x4*)(in + i + 4);
  u16x8 o;
#pragma unroll
  for (int e = 0; e < 4; e++) {
    o[e]     = f2bf(a[e]);
    o[e + 4] = f2bf(b[e]);
  }
  *(u16x8*)(out + i) = o;
}

// ---------------------------------------------------------------------------
// Pure-bf16 GEMM (m97 structure + T2 both-sides swizzle):
// out[M,N] = A[M,K](lda) @ W[N,K]^T + bias
// MODE 0: bias -> bf16.  MODE 2: bias+GELU(tanh) -> bf16.
// ---------------------------------------------------------------------------
template<int MODE>
__global__ __launch_bounds__(256)
void te_gemm_bb(const uint16_t* __restrict__ A, int lda,
                const uint16_t* __restrict__ W, const float* __restrict__ bias,
                uint16_t* __restrict__ outB, int M, int N, int K)
{
  __shared__ uint16_t la[128 * 64];
  __shared__ uint16_t lb[128 * 64];
  const int tid = threadIdx.x;
  const int w = tid >> 6, l = tid & 63;
  const int lr = l & 15, lg = l >> 4;
  const int tm = blockIdx.y * 128, tn = blockIdx.x * 128;
  const int srow = l >> 3;
  const int scol = ((l & 7) ^ srow) * 8;           // pre-swizzled source chunk
  const int wr = (w >> 1) * 64, wc = (w & 1) * 64;

  f32x4 acc[4][4] = {};

  for (int k0 = 0; k0 < K; k0 += 64) {
#pragma unroll
    for (int c = 0; c < 4; c++) {
      const int rb = (c * 4 + w) * 8;
      const uint16_t* ga = A + (size_t)(tm + rb + srow) * lda + (k0 + scol);
      __builtin_amdgcn_global_load_lds((gbl_void*)(uintptr_t)ga,
                                       (lds_void*)(la + rb * 64), 16, 0, 0);
      const uint16_t* gw = W + (size_t)(tn + rb + srow) * K + (k0 + scol);
      __builtin_amdgcn_global_load_lds((gbl_void*)(uintptr_t)gw,
                                       (lds_void*)(lb + rb * 64), 16, 0, 0);
    }
    __syncthreads();
#pragma unroll
    for (int kk = 0; kk < 2; kk++) {
      u16x8 af[4], bfr[4];
#pragma unroll
      for (int i = 0; i < 4; i++) {
        const int row = wr + i * 16 + lr;
        af[i] = *(const u16x8*)&la[row * 64 + (((kk * 4 + lg) ^ (lr & 7)) << 3)];
      }
#pragma unroll
      for (int j = 0; j < 4; j++) {
        const int row = wc + j * 16 + lr;
        bfr[j] = *(const u16x8*)&lb[row * 64 + (((kk * 4 + lg) ^ (lr & 7)) << 3)];
      }
      __builtin_amdgcn_s_setprio(1);
#pragma unroll
      for (int i = 0; i < 4; i++)
#pragma unroll
        for (int j = 0; j < 4; j++)
          acc[i][j] = mfma16(af[i], bfr[j], acc[i][j]);
      __builtin_amdgcn_s_setprio(0);
    }
    __syncthreads();
  }

  float bv[4];
#pragma unroll
  for (int j = 0; j < 4; j++) bv[j] = bias[tn + wc + j * 16 + lr];
#pragma unroll
  for (int i = 0; i < 4; i++)
#pragma unroll
    for (int j = 0; j < 4; j++)
#pragma unroll
      for (int r = 0; r < 4; r++) {
        const int row = tm + wr + i * 16 + lg * 4 + r;
        const int col = tn + wc + j * 16 + lr;
        float v = acc[i][j][r] + bv[j];
        if (MODE == 2) {
          const float u = 0.7978845608028654f * v * (1.0f + 0.044715f * v * v);
          const float t = 1.0f - 2.0f / (__expf(2.0f * u) + 1.0f);
          v = 0.5f * v * (1.0f + t);
        }
        outB[(size_t)row * N + col] = f2bf(v);
      }
}

// ---------------------------------------------------------------------------
// softmax + pack macro (per q-group), S^T layout: lane lr owns q-row iQ.
// ---------------------------------------------------------------------------
#define SOFTMAX_PACK(S, MR, SDQ, ACC, IQ, P2)                                  \
  {                                                                            \
    const float f0 = (float)((IQ) - jt - lg * 4);                              \
    float mt = -1e30f;                                                         \
    _Pragma("unroll")                                                          \
    for (int n = 0; n < 4; n++) {                                              \
      const float fj = f0 - (float)(n * 16);                                   \
      _Pragma("unroll")                                                        \
      for (int r = 0; r < 4; r++) {                                            \
        const float v = fmaf(S[n][r], scl2e, -slope2e * fabsf(fj - (float)r)); \
        S[n][r] = v;                                                           \
        mt = fmaxf(mt, v);                                                     \
      }                                                                        \
    }                                                                          \
    mt = fmaxf(mt, __shfl_xor(mt, 16));                                        \
    mt = fmaxf(mt, __shfl_xor(mt, 32));                                        \
    if (!__all(mt <= MR)) {                                                    \
      const float mN = fmaxf(MR, mt);                                          \
      const float fq = exp2f(MR - mN);                                         \
      MR = mN;                                                                 \
      SDQ *= fq;                                                               \
      float fA[4];                                                             \
      _Pragma("unroll")                                                        \
      for (int r = 0; r < 4; r++) fA[r] = __shfl(fq, lg * 4 + r);              \
      _Pragma("unroll")                                                        \
      for (int n = 0; n < 4; n++)                                              \
        _Pragma("unroll")                                                      \
        for (int r = 0; r < 4; r++) ACC[n][r] *= fA[r];                        \
    }                                                                          \
    float rs = 0.0f;                                                           \
    _Pragma("unroll")                                                          \
    for (int n = 0; n < 4; n++)                                                \
      _Pragma("unroll")                                                        \
      for (int r = 0; r < 4; r++) {                                            \
        const float p = exp2f(S[n][r] - MR);                                   \
        S[n][r] = p;                                                           \
        rs += p;                                                               \
      }                                                                        \
    rs += __shfl_xor(rs, 16);                                                  \
    rs += __shfl_xor(rs, 32);                                                  \
    SDQ += rs;                                                                 \
    _Pragma("unroll")                                                          \
    for (int n = 0; n < 4; n++) {                                              \
      P2[n][0] = cvt_pk_bf16(S[n][0], S[n][1]);                                \
      P2[n][1] = cvt_pk_bf16(S[n][2], S[n][3]);                                \
    }                                                                          \
  }

// ---------------------------------------------------------------------------
// Fused attention v3: QBLK=128 (2 q-groups/block, staging amortized 2x).
// Swapped QK^T, exp2 domain, exact defer-max (diag-first), in-register P.
// qkv [B*T, 3072] bf16; grid (bh=256, qt=4). In-place q output.
// ---------------------------------------------------------------------------
__global__ __launch_bounds__(256)
void te_attn(uint16_t* __restrict__ qkv)
{
  __shared__ uint16_t kl[64 * 64];   // K[j][d] swizzled chunks
  __shared__ uint16_t vt[64 * 64];   // V^T[d][j] swizzled chunks
  const int tid = threadIdx.x;
  const int w = tid >> 6, l = tid & 63;
  const int lr = l & 15, lg = l >> 4;
  const int bh = blockIdx.x, qt = blockIdx.y;   // qt 0..3
  const int h = bh & 15, b = bh >> 4;

  const int iQ0 = qt * 128 + w * 16 + lr;       // group 0; group 1 = +64
  u16x8 qf[2][2];
#pragma unroll
  for (int g = 0; g < 2; g++) {
    const size_t qoff = ((size_t)(b * 512 + iQ0 + g * 64)) * 3072 + h * 64 + lg * 8;
    qf[g][0] = *(const u16x8*)&qkv[qoff];
    qf[g][1] = *(const u16x8*)&qkv[qoff + 32];
  }
  const float LOG2E = 1.4426950408889634f;
  const float scl2e = 0.125f * LOG2E;
  const float slope2e = exp2f(-0.5f * (float)(h + 1)) * LOG2E;

  const int sjb = tid >> 3;           // 0..31 (j within half-tile)
  const int sd0 = (tid & 7) * 8;      // d chunk start

  float mR0 = -1e30f, sdq0 = 0.0f, mR1 = -1e30f, sdq1 = 0.0f;
  f32x4 acc0[4] = {}, acc1[4] = {};

  // prologue: load first (diagonal-of-group-0) tile into regs
  u16x8 kreg[2], vreg[2];
  {
    const int jt0 = (qt * 2) * 64;
#pragma unroll
    for (int cc = 0; cc < 2; cc++) {
      const int j = sjb + cc * 32;
      const size_t rbase = ((size_t)(b * 512 + jt0 + j)) * 3072 + h * 64 + sd0;
      kreg[cc] = *(const u16x8*)&qkv[rbase + 1024];
      vreg[cc] = *(const u16x8*)&qkv[rbase + 2048];
    }
  }

  for (int step = 0; step < 8; step++) {
    const int jt = ((qt * 2 + step) & 7) * 64;
    // ---- write staged regs to LDS ----
#pragma unroll
    for (int cc = 0; cc < 2; cc++) {
      const int j = sjb + cc * 32;
      *(u16x8*)&kl[j * 64 + (((sd0 >> 3) ^ (j & 7)) << 3)] = kreg[cc];
      const int cV = (((j >> 3) ^ (sd0 >> 3)) << 3) + (j & 7);
#pragma unroll
      for (int e = 0; e < 8; e++) vt[(sd0 + e) * 64 + cV] = vreg[cc][e];
    }
    __syncthreads();
    // ---- issue next tile's global loads (hidden under compute) ----
    if (step < 7) {
      const int jtn = ((qt * 2 + step + 1) & 7) * 64;
#pragma unroll
      for (int cc = 0; cc < 2; cc++) {
        const int j = sjb + cc * 32;
        const size_t rbase = ((size_t)(b * 512 + jtn + j)) * 3072 + h * 64 + sd0;
        kreg[cc] = *(const u16x8*)&qkv[rbase + 1024];
        vreg[cc] = *(const u16x8*)&qkv[rbase + 2048];
      }
    }

    // ---- S^T = mfma(K, Q) for both q-groups (K-frags shared) ----
    f32x4 s0[4] = {}, s1[4] = {};
#pragma unroll
    for (int kk = 0; kk < 2; kk++) {
      u16x8 kf[4];
#pragma unroll
      for (int n = 0; n < 4; n++) {
        const int row = n * 16 + lr;
        kf[n] = *(const u16x8*)&kl[row * 64 + (((kk * 4 + lg) ^ (lr & 7)) << 3)];
      }
      __builtin_amdgcn_s_setprio(1);
#pragma unroll
      for (int n = 0; n < 4; n++) {
        s0[n] = mfma16(kf[n], qf[0][kk], s0[n]);
        s1[n] = mfma16(kf[n], qf[1][kk], s1[n]);
      }
      __builtin_amdgcn_s_setprio(0);
    }

    // ---- softmax + pack per group ----
    uint32_t P2a[4][2], P2b[4][2];
    SOFTMAX_PACK(s0, mR0, sdq0, acc0, iQ0,      P2a);
    SOFTMAX_PACK(s1, mR1, sdq1, acc1, iQ0 + 64, P2b);

    // ---- redistribute to A-frag layout + PV (V-frags shared) ----
#pragma unroll
    for (int kk = 0; kk < 2; kk++) {
      uint32_t pw0[4], pw1[4];
#pragma unroll
      for (int t = 0; t < 4; t++) {
        const int srcLane = lr + 16 * ((lg & 1) * 2 + (t >> 1));
        const uint32_t a0 = __shfl(P2a[2 * kk + 0][t & 1], srcLane);
        const uint32_t b0 = __shfl(P2a[2 * kk + 1][t & 1], srcLane);
        pw0[t] = (lg >> 1) ? b0 : a0;
        const uint32_t a1 = __shfl(P2b[2 * kk + 0][t & 1], srcLane);
        const uint32_t b1 = __shfl(P2b[2 * kk + 1][t & 1], srcLane);
        pw1[t] = (lg >> 1) ? b1 : a1;
      }
      u32x4 q0 = { pw0[0], pw0[1], pw0[2], pw0[3] };
      u32x4 q1 = { pw1[0], pw1[1], pw1[2], pw1[3] };
      u16x8 pf0 = __builtin_bit_cast(u16x8, q0);
      u16x8 pf1 = __builtin_bit_cast(u16x8, q1);
      u16x8 vf[4];
#pragma unroll
      for (int n = 0; n < 4; n++) {
        const int row = n * 16 + lr;
        vf[n] = *(const u16x8*)&vt[row * 64 + ((((kk * 4 + lg) ^ (2 * n + (lr >> 3))) & 7) << 3)];
      }
      __builtin_amdgcn_s_setprio(1);
#pragma unroll
      for (int n = 0; n < 4; n++) {
        acc0[n] = mfma16(pf0, vf[n], acc0[n]);
        acc1[n] = mfma16(pf1, vf[n], acc1[n]);
      }
      __builtin_amdgcn_s_setprio(0);
    }
    __syncthreads();
  }

  // ---- epilogue: O[i][d] for both groups ----
  {
    float sdA[4];
#pragma unroll
    for (int r = 0; r < 4; r++) sdA[r] = 1.0f / __shfl(sdq0, lg * 4 + r);
#pragma unroll
    for (int n = 0; n < 4; n++)
#pragma unroll
      for (int r = 0; r < 4; r++) {
        const int i = qt * 128 + w * 16 + lg * 4 + r;
        const int d = h * 64 + n * 16 + lr;
        qkv[((size_t)(b * 512 + i)) * 3072 + d] = f2bf(acc0[n][r] * sdA[r]);
      }
  }
  {
    float sdA[4];
#pragma unroll
    for (int r = 0; r < 4; r++) sdA[r] = 1.0f / __shfl(sdq1, lg * 4 + r);
#pragma unroll
    for (int n = 0; n < 4; n++)
#pragma unroll
      for (int r = 0; r < 4; r++) {
        const int i = qt * 128 + 64 + w * 16 + lg * 4 + r;
        const int d = h * 64 + n * 16 + lr;
        qkv[((size_t)(b * 512 + i)) * 3072 + d] = f2bf(acc1[n][r] * sdA[r]);
      }
  }
}

// ---------------------------------------------------------------------------
// LN (bf16 residual): x = h(bf16) + delta(bf16) in f32; y = LN(x)*w + b.
// FINAL=0: writes hout (bf16, aliases h).  FINAL=1: writes fout (f32 d_out).
// ---------------------------------------------------------------------------
template<int FINAL>
__global__ __launch_bounds__(256)
void te_ln(const uint16_t* __restrict__ h, const uint16_t* __restrict__ delta,
           const float* __restrict__ w, const float* __restrict__ b,
           uint16_t* __restrict__ hout, float* __restrict__ fout)
{
  const int row = blockIdx.x, t = threadIdx.x;
  const size_t base = (size_t)row * 1024 + t * 4;
  u16x4 hv = *(const u16x4*)&h[base];
  u16x4 dv = *(const u16x4*)&delta[base];
  float x[4];
#pragma unroll
  for (int i = 0; i < 4; i++) x[i] = bf2f(hv[i]) + bf2f(dv[i]);
  float s = x[0] + x[1] + x[2] + x[3];
  float ss = x[0]*x[0] + x[1]*x[1] + x[2]*x[2] + x[3]*x[3];
#pragma unroll
  for (int msk = 32; msk >= 1; msk >>= 1) {
    s  += __shfl_xor(s, msk);
    ss += __shfl_xor(ss, msk);
  }
  __shared__ float rs[4], rq[4];
  const int wv = t >> 6;
  if ((t & 63) == 0) { rs[wv] = s; rq[wv] = ss; }
  __syncthreads();
  s  = rs[0] + rs[1] + rs[2] + rs[3];
  ss = rq[0] + rq[1] + rq[2] + rq[3];
  const float mean = s * (1.0f / 1024.0f);
  const float var  = ss * (1.0f / 1024.0f) - mean * mean;
  const float rstd = rsqrtf(var + 1e-5f);
  f32x4 wv4 = *(const f32x4*)&w[t * 4];
  f32x4 bv4 = *(const f32x4*)&b[t * 4];
  if (FINAL == 0) {
    u16x4 bo;
#pragma unroll
    for (int i = 0; i < 4; i++)
      bo[i] = f2bf((x[i] - mean) * rstd * wv4[i] + bv4[i]);
    *(u16x4*)&hout[base] = bo;
  } else {
    f32x4 yo;
#pragma unroll
    for (int i = 0; i < 4; i++)
      yo[i] = (x[i] - mean) * rstd * wv4[i] + bv4[i];
    *(f32x4*)&fout[base] = yo;
  }
}

// ---------------------------------------------------------------------------
extern "C" void kernel_launch(void* const* d_in, const int* in_sizes, int n_in,
                              void* d_out, int out_size, void* d_ws, size_t ws_size,
                              hipStream_t stream)
{
  (void)in_sizes; (void)n_in; (void)out_size; (void)ws_size;
  const float* x     = (const float*)d_in[0];
  const float* bn_w  = (const float*)d_in[1];
  const float* bn_b  = (const float*)d_in[2];
  const float* qkv_w = (const float*)d_in[3];
  const float* qkv_b = (const float*)d_in[4];
  const float* out_w = (const float*)d_in[5];
  const float* out_b = (const float*)d_in[6];
  const float* ln1_w = (const float*)d_in[7];
  const float* ln1_b = (const float*)d_in[8];
  const float* ln2_w = (const float*)d_in[9];
  const float* ln2_b = (const float*)d_in[10];
  const float* ff1_w = (const float*)d_in[11];
  const float* ff1_b = (const float*)d_in[12];
  const float* ff2_w = (const float*)d_in[13];
  const float* ff2_b = (const float*)d_in[14];

  char* ws = (char*)d_ws;
  uint16_t* h_bf    = (uint16_t*)ws;                      // 16 MiB @ 0
  uint16_t* qkvb    = (uint16_t*)(ws + (16u  << 20));     // 48 MiB @ 16
  uint16_t* scrA    = (uint16_t*)(ws + (64u  << 20));     // 16 MiB @ 64 (also x_bf)
  uint16_t* qkvw_bf = (uint16_t*)(ws + (80u  << 20));     // 36 MiB @ 80
  uint16_t* ff2w_bf = (uint16_t*)(ws + (116u << 20));     // 12 MiB @ 116
  uint16_t* bnw_bf  = (uint16_t*)(ws + (128u << 20));     //  2 MiB @ 128 (130 total)
  // d_out as scratch for weights that die before the final LN writes d_out:
  uint16_t* outw_bf = (uint16_t*)d_out;                   // 12 MiB @ 0
  uint16_t* ff1w_bf = (uint16_t*)((char*)d_out + (12u << 20)); // 12 MiB @ 12
  float*    outf    = (float*)d_out;                      // final fp32 output

  const int M = 8192;
  dim3 blk(256);

  // one-time fp32 -> bf16 conversions (weights + x)
  te_cvt<<<dim3(18874368 / 2048), blk, 0, stream>>>(qkv_w, qkvw_bf);
  te_cvt<<<dim3(6291456  / 2048), blk, 0, stream>>>(out_w, outw_bf);
  te_cvt<<<dim3(6291456  / 2048), blk, 0, stream>>>(ff1_w, ff1w_bf);
  te_cvt<<<dim3(6291456  / 2048), blk, 0, stream>>>(ff2_w, ff2w_bf);
  te_cvt<<<dim3(1048576  / 2048), blk, 0, stream>>>(bn_w,  bnw_bf);
  te_cvt<<<dim3(8388608  / 2048), blk, 0, stream>>>(x,     scrA);

  // bottleneck: h0 = x @ bn_w^T + bn_b  (bf16 residual)
  te_gemm_bb<0><<<dim3(8, 64), blk, 0, stream>>>(scrA, 1024, bnw_bf, bn_b,
                                                 h_bf, M, 1024, 1024);

  for (int l = 0; l < 6; l++) {
    te_gemm_bb<0><<<dim3(24, 64), blk, 0, stream>>>(
        h_bf, 1024, qkvw_bf + (size_t)l * 3072 * 1024, qkv_b + l * 3072,
        qkvb, M, 3072, 1024);
    te_attn<<<dim3(256, 4), blk, 0, stream>>>(qkvb);
    te_gemm_bb<0><<<dim3(8, 64), blk, 0, stream>>>(
        qkvb, 3072, outw_bf + (size_t)l * 1024 * 1024, out_b + l * 1024,
        scrA, M, 1024, 1024);
    te_ln<0><<<dim3(8192), blk, 0, stream>>>(h_bf, scrA, ln1_w + l * 1024, ln1_b + l * 1024,
                                             h_bf, nullptr);
    te_gemm_bb<2><<<dim3(8, 64), blk, 0, stream>>>(
        h_bf, 1024, ff1w_bf + (size_t)l * 1024 * 1024, ff1_b + l * 1024,
        scrA, M, 1024, 1024);
    te_gemm_bb<0><<<dim3(8, 64), blk, 0, stream>>>(
        scrA, 1024, ff2w_bf + (size_t)l * 1024 * 1024, ff2_b + l * 1024,
        qkvb, M, 1024, 1024);
    if (l == 5) {
      te_ln<1><<<dim3(8192), blk, 0, stream>>>(h_bf, qkvb, ln2_w + l * 1024, ln2_b + l * 1024,
                                               nullptr, outf);
    } else {
      te_ln<0><<<dim3(8192), blk, 0, stream>>>(h_bf, qkvb, ln2_w + l * 1024, ln2_b + l * 1024,
                                               h_bf, nullptr);
    }
  }
}

// Round 8
// 1403.528 us; speedup vs baseline: 1.4372x; 1.0501x over previous
//
#include <hip/hip_runtime.h>
#include <stdint.h>

#define DEV static __device__ __forceinline__

typedef __attribute__((ext_vector_type(8))) uint16_t u16x8;
typedef __attribute__((ext_vector_type(4))) uint16_t u16x4;
typedef __attribute__((ext_vector_type(4))) uint32_t u32x4;
typedef __attribute__((ext_vector_type(4))) float    f32x4;
typedef __attribute__((ext_vector_type(8))) __bf16   bf16x8;

typedef __attribute__((address_space(3))) void lds_void;
typedef __attribute__((address_space(1))) void gbl_void;

DEV float bf2f(uint16_t u){
  union { uint32_t i; float f; } v; v.i = ((uint32_t)u) << 16; return v.f;
}
DEV uint16_t f2bf(float f){ return __builtin_bit_cast(uint16_t, (__bf16)f); }
DEV f32x4 mfma16(u16x8 a, u16x8 b, f32x4 c){
  return __builtin_amdgcn_mfma_f32_16x16x32_bf16(
      __builtin_bit_cast(bf16x8, a), __builtin_bit_cast(bf16x8, b), c, 0, 0, 0);
}
DEV uint32_t cvt_pk_bf16(float lo, float hi){
  uint32_t r;
  asm("v_cvt_pk_bf16_f32 %0, %1, %2" : "=v"(r) : "v"(lo), "v"(hi));
  return r;
}

// ---------------------------------------------------------------------------
// fp32 -> bf16 elementwise convert, 8 elems/thread.
// ---------------------------------------------------------------------------
__global__ __launch_bounds__(256)
void te_cvt(const float* __restrict__ in, uint16_t* __restrict__ out)
{
  const size_t i = ((size_t)blockIdx.x * 256 + threadIdx.x) * 8;
  f32x4 a = *(const f32x4*)(in + i);
  f32x4 b = *(const f32x4*)(in + i + 4);
  u16x8 o;
#pragma unroll
  for (int e = 0; e < 4; e++) {
    o[e]     = f2bf(a[e]);
    o[e + 4] = f2bf(b[e]);
  }
  *(u16x8*)(out + i) = o;
}

// ---------------------------------------------------------------------------
// Deep-pipelined GEMM (8-phase style): out[M=8192,N] = A[M,K](lda)@W[N,K]^T + b
// 256x128 tile, BK=64, 512 thr (8 waves, 2M x 4N), double-buffered LDS 96KB,
// counted vmcnt (never 0 in loop), raw s_barrier (no drain), 4 phases/K-tile,
// setprio around MFMA clusters, T2 chunk-XOR swizzle, bijective XCD swizzle.
// MODE 0: bias -> bf16.  MODE 2: bias + GELU(tanh) -> bf16.
// ---------------------------------------------------------------------------
template<int MODE>
__global__ __launch_bounds__(512)
void te_gemm256(const uint16_t* __restrict__ A, int lda,
                const uint16_t* __restrict__ Wm, const float* __restrict__ bias,
                uint16_t* __restrict__ outB, int N, int K)
{
  constexpr int SZA = 256 * 64;           // A tile in uint16
  constexpr int SZB = 128 * 64;           // B tile in uint16
  __shared__ uint16_t lds[2 * (SZA + SZB)];   // 96 KiB

  const int tid = threadIdx.x;
  const int w = tid >> 6, l = tid & 63;
  const int lr = l & 15, lg = l >> 4;
  const int wr = w >> 2, wc = w & 3;      // 2M x 4N wave grid
  const int srow = l >> 3, chunk = l & 7;

  // bijective XCD swizzle on flat block id (gridDim.x % 8 == 0)
  const int nb = gridDim.x;
  const int bid = blockIdx.x;
  const int lid = (bid & 7) * (nb >> 3) + (bid >> 3);
  const int nx = N >> 7;
  const int tm = (lid / nx) << 8;
  const int tn = (lid % nx) << 7;

  const int rw = w * 8 + srow;            // 0..63 stage row within 64-row group
  const int sc = (chunk ^ srow) << 3;     // pre-swizzled source col chunk

  auto stage = [&](int kt, int p) {
    const int k0 = kt << 6;
    uint16_t* bufA = lds + p * (SZA + SZB);
    uint16_t* bufB = bufA + SZA;
#pragma unroll
    for (int c = 0; c < 4; c++) {
      const uint16_t* ga = A + (size_t)(tm + c * 64 + rw) * lda + (k0 + sc);
      __builtin_amdgcn_global_load_lds((gbl_void*)(uintptr_t)ga,
          (lds_void*)(bufA + (c * 64 + w * 8) * 64), 16, 0, 0);
    }
#pragma unroll
    for (int c = 0; c < 2; c++) {
      const uint16_t* gw = Wm + (size_t)(tn + c * 64 + rw) * K + (k0 + sc);
      __builtin_amdgcn_global_load_lds((gbl_void*)(uintptr_t)gw,
          (lds_void*)(bufB + (c * 64 + w * 8) * 64), 16, 0, 0);
    }
  };

  f32x4 acc[8][2] = {};
  const int nt = K >> 6;

  stage(0, 0);
  for (int t = 0; t < nt; ++t) {
    const int cur = t & 1;
    uint16_t* bufA = lds + cur * (SZA + SZB);
    uint16_t* bufB = bufA + SZA;

    asm volatile("" ::: "memory");        // pin: stage stays after prior reads
    if (t + 1 < nt) {
      stage(t + 1, cur ^ 1);
      asm volatile("s_waitcnt vmcnt(6)" ::: "memory");  // tile t landed; t+1 in flight
    } else {
      asm volatile("s_waitcnt vmcnt(0)" ::: "memory");
    }
    __builtin_amdgcn_s_barrier();         // all waves gated -> tile t complete

    // B fragments once per K-tile (quadrant-independent)
    u16x8 bf[2][2];
#pragma unroll
    for (int fc = 0; fc < 2; fc++)
#pragma unroll
      for (int kk = 0; kk < 2; kk++) {
        const int nrow = wc * 32 + fc * 16 + lr;
        bf[fc][kk] = *(const u16x8*)&bufB[nrow * 64 + (((kk * 4 + lg) ^ (lr & 7)) << 3)];
      }

    // 4 phases: M-quadrants of this wave's 128-row strip
#pragma unroll
    for (int q = 0; q < 4; q++) {
      u16x8 af[2][2];
#pragma unroll
      for (int i = 0; i < 2; i++)
#pragma unroll
        for (int kk = 0; kk < 2; kk++) {
          const int row = wr * 128 + (q * 2 + i) * 16 + lr;
          af[i][kk] = *(const u16x8*)&bufA[row * 64 + (((kk * 4 + lg) ^ (lr & 7)) << 3)];
        }
      __builtin_amdgcn_s_barrier();       // phase alignment (wave role-split)
      __builtin_amdgcn_s_setprio(1);
#pragma unroll
      for (int i = 0; i < 2; i++)
#pragma unroll
        for (int fc = 0; fc < 2; fc++) {
          acc[q * 2 + i][fc] = mfma16(af[i][0], bf[fc][0], acc[q * 2 + i][fc]);
          acc[q * 2 + i][fc] = mfma16(af[i][1], bf[fc][1], acc[q * 2 + i][fc]);
        }
      __builtin_amdgcn_s_setprio(0);
      __builtin_amdgcn_s_barrier();       // phase end; last one = write-protect
    }
  }

  // epilogue
  float bv[2];
#pragma unroll
  for (int fc = 0; fc < 2; fc++) bv[fc] = bias[tn + wc * 32 + fc * 16 + lr];
#pragma unroll
  for (int fr = 0; fr < 8; fr++)
#pragma unroll
    for (int fc = 0; fc < 2; fc++)
#pragma unroll
      for (int r = 0; r < 4; r++) {
        const int row = tm + wr * 128 + fr * 16 + lg * 4 + r;
        const int col = tn + wc * 32 + fc * 16 + lr;
        float v = acc[fr][fc][r] + bv[fc];
        if (MODE == 2) {
          const float u = 0.7978845608028654f * v * (1.0f + 0.044715f * v * v);
          const float t = 1.0f - 2.0f / (__expf(2.0f * u) + 1.0f);
          v = 0.5f * v * (1.0f + t);
        }
        outB[(size_t)row * N + col] = f2bf(v);
      }
}

// ---------------------------------------------------------------------------
// softmax + pack macro (per q-group), S^T layout: lane lr owns q-row iQ.
// ---------------------------------------------------------------------------
#define SOFTMAX_PACK(S, MR, SDQ, ACC, IQ, P2)                                  \
  {                                                                            \
    const float f0 = (float)((IQ) - jt - lg * 4);                              \
    float mt = -1e30f;                                                         \
    _Pragma("unroll")                                                          \
    for (int n = 0; n < 4; n++) {                                              \
      const float fj = f0 - (float)(n * 16);                                   \
      _Pragma("unroll")                                                        \
      for (int r = 0; r < 4; r++) {                                            \
        const float v = fmaf(S[n][r], scl2e, -slope2e * fabsf(fj - (float)r)); \
        S[n][r] = v;                                                           \
        mt = fmaxf(mt, v);                                                     \
      }                                                                        \
    }                                                                          \
    mt = fmaxf(mt, __shfl_xor(mt, 16));                                        \
    mt = fmaxf(mt, __shfl_xor(mt, 32));                                        \
    if (!__all(mt <= MR)) {                                                    \
      const float mN = fmaxf(MR, mt);                                          \
      const float fq = exp2f(MR - mN);                                         \
      MR = mN;                                                                 \
      SDQ *= fq;                                                               \
      float fA[4];                                                             \
      _Pragma("unroll")                                                        \
      for (int r = 0; r < 4; r++) fA[r] = __shfl(fq, lg * 4 + r);              \
      _Pragma("unroll")                                                        \
      for (int n = 0; n < 4; n++)                                              \
        _Pragma("unroll")                                                      \
        for (int r = 0; r < 4; r++) ACC[n][r] *= fA[r];                        \
    }                                                                          \
    float rs = 0.0f;                                                           \
    _Pragma("unroll")                                                          \
    for (int n = 0; n < 4; n++)                                                \
      _Pragma("unroll")                                                        \
      for (int r = 0; r < 4; r++) {                                            \
        const float p = exp2f(S[n][r] - MR);                                   \
        S[n][r] = p;                                                           \
        rs += p;                                                               \
      }                                                                        \
    rs += __shfl_xor(rs, 16);                                                  \
    rs += __shfl_xor(rs, 32);                                                  \
    SDQ += rs;                                                                 \
    _Pragma("unroll")                                                          \
    for (int n = 0; n < 4; n++) {                                              \
      P2[n][0] = cvt_pk_bf16(S[n][0], S[n][1]);                                \
      P2[n][1] = cvt_pk_bf16(S[n][2], S[n][3]);                                \
    }                                                                          \
  }

// ---------------------------------------------------------------------------
// Fused attention v3: QBLK=128 (2 q-groups/block, staging amortized 2x).
// Swapped QK^T, exp2 domain, exact defer-max (diag-first), in-register P.
// qkv [B*T, 3072] bf16; grid (bh=256, qt=4). In-place q output.
// ---------------------------------------------------------------------------
__global__ __launch_bounds__(256)
void te_attn(uint16_t* __restrict__ qkv)
{
  __shared__ uint16_t kl[64 * 64];   // K[j][d] swizzled chunks
  __shared__ uint16_t vt[64 * 64];   // V^T[d][j] swizzled chunks
  const int tid = threadIdx.x;
  const int w = tid >> 6, l = tid & 63;
  const int lr = l & 15, lg = l >> 4;
  const int bh = blockIdx.x, qt = blockIdx.y;   // qt 0..3
  const int h = bh & 15, b = bh >> 4;

  const int iQ0 = qt * 128 + w * 16 + lr;       // group 0; group 1 = +64
  u16x8 qf[2][2];
#pragma unroll
  for (int g = 0; g < 2; g++) {
    const size_t qoff = ((size_t)(b * 512 + iQ0 + g * 64)) * 3072 + h * 64 + lg * 8;
    qf[g][0] = *(const u16x8*)&qkv[qoff];
    qf[g][1] = *(const u16x8*)&qkv[qoff + 32];
  }
  const float LOG2E = 1.4426950408889634f;
  const float scl2e = 0.125f * LOG2E;
  const float slope2e = exp2f(-0.5f * (float)(h + 1)) * LOG2E;

  const int sjb = tid >> 3;           // 0..31 (j within half-tile)
  const int sd0 = (tid & 7) * 8;      // d chunk start

  float mR0 = -1e30f, sdq0 = 0.0f, mR1 = -1e30f, sdq1 = 0.0f;
  f32x4 acc0[4] = {}, acc1[4] = {};

  // prologue: load first (diagonal-of-group-0) tile into regs
  u16x8 kreg[2], vreg[2];
  {
    const int jt0 = (qt * 2) * 64;
#pragma unroll
    for (int cc = 0; cc < 2; cc++) {
      const int j = sjb + cc * 32;
      const size_t rbase = ((size_t)(b * 512 + jt0 + j)) * 3072 + h * 64 + sd0;
      kreg[cc] = *(const u16x8*)&qkv[rbase + 1024];
      vreg[cc] = *(const u16x8*)&qkv[rbase + 2048];
    }
  }

  for (int step = 0; step < 8; step++) {
    const int jt = ((qt * 2 + step) & 7) * 64;
    // ---- write staged regs to LDS ----
#pragma unroll
    for (int cc = 0; cc < 2; cc++) {
      const int j = sjb + cc * 32;
      *(u16x8*)&kl[j * 64 + (((sd0 >> 3) ^ (j & 7)) << 3)] = kreg[cc];
      const int cV = (((j >> 3) ^ (sd0 >> 3)) << 3) + (j & 7);
#pragma unroll
      for (int e = 0; e < 8; e++) vt[(sd0 + e) * 64 + cV] = vreg[cc][e];
    }
    __syncthreads();
    // ---- issue next tile's global loads (hidden under compute) ----
    if (step < 7) {
      const int jtn = ((qt * 2 + step + 1) & 7) * 64;
#pragma unroll
      for (int cc = 0; cc < 2; cc++) {
        const int j = sjb + cc * 32;
        const size_t rbase = ((size_t)(b * 512 + jtn + j)) * 3072 + h * 64 + sd0;
        kreg[cc] = *(const u16x8*)&qkv[rbase + 1024];
        vreg[cc] = *(const u16x8*)&qkv[rbase + 2048];
      }
    }

    // ---- S^T = mfma(K, Q) for both q-groups (K-frags shared) ----
    f32x4 s0[4] = {}, s1[4] = {};
#pragma unroll
    for (int kk = 0; kk < 2; kk++) {
      u16x8 kf[4];
#pragma unroll
      for (int n = 0; n < 4; n++) {
        const int row = n * 16 + lr;
        kf[n] = *(const u16x8*)&kl[row * 64 + (((kk * 4 + lg) ^ (lr & 7)) << 3)];
      }
      __builtin_amdgcn_s_setprio(1);
#pragma unroll
      for (int n = 0; n < 4; n++) {
        s0[n] = mfma16(kf[n], qf[0][kk], s0[n]);
        s1[n] = mfma16(kf[n], qf[1][kk], s1[n]);
      }
      __builtin_amdgcn_s_setprio(0);
    }

    // ---- softmax + pack per group ----
    uint32_t P2a[4][2], P2b[4][2];
    SOFTMAX_PACK(s0, mR0, sdq0, acc0, iQ0,      P2a);
    SOFTMAX_PACK(s1, mR1, sdq1, acc1, iQ0 + 64, P2b);

    // ---- redistribute to A-frag layout + PV (V-frags shared) ----
#pragma unroll
    for (int kk = 0; kk < 2; kk++) {
      uint32_t pw0[4], pw1[4];
#pragma unroll
      for (int t = 0; t < 4; t++) {
        const int srcLane = lr + 16 * ((lg & 1) * 2 + (t >> 1));
        const uint32_t a0 = __shfl(P2a[2 * kk + 0][t & 1], srcLane);
        const uint32_t b0 = __shfl(P2a[2 * kk + 1][t & 1], srcLane);
        pw0[t] = (lg >> 1) ? b0 : a0;
        const uint32_t a1 = __shfl(P2b[2 * kk + 0][t & 1], srcLane);
        const uint32_t b1 = __shfl(P2b[2 * kk + 1][t & 1], srcLane);
        pw1[t] = (lg >> 1) ? b1 : a1;
      }
      u32x4 q0 = { pw0[0], pw0[1], pw0[2], pw0[3] };
      u32x4 q1 = { pw1[0], pw1[1], pw1[2], pw1[3] };
      u16x8 pf0 = __builtin_bit_cast(u16x8, q0);
      u16x8 pf1 = __builtin_bit_cast(u16x8, q1);
      u16x8 vf[4];
#pragma unroll
      for (int n = 0; n < 4; n++) {
        const int row = n * 16 + lr;
        vf[n] = *(const u16x8*)&vt[row * 64 + ((((kk * 4 + lg) ^ (2 * n + (lr >> 3))) & 7) << 3)];
      }
      __builtin_amdgcn_s_setprio(1);
#pragma unroll
      for (int n = 0; n < 4; n++) {
        acc0[n] = mfma16(pf0, vf[n], acc0[n]);
        acc1[n] = mfma16(pf1, vf[n], acc1[n]);
      }
      __builtin_amdgcn_s_setprio(0);
    }
    __syncthreads();
  }

  // ---- epilogue: O[i][d] for both groups ----
  {
    float sdA[4];
#pragma unroll
    for (int r = 0; r < 4; r++) sdA[r] = 1.0f / __shfl(sdq0, lg * 4 + r);
#pragma unroll
    for (int n = 0; n < 4; n++)
#pragma unroll
      for (int r = 0; r < 4; r++) {
        const int i = qt * 128 + w * 16 + lg * 4 + r;
        const int d = h * 64 + n * 16 + lr;
        qkv[((size_t)(b * 512 + i)) * 3072 + d] = f2bf(acc0[n][r] * sdA[r]);
      }
  }
  {
    float sdA[4];
#pragma unroll
    for (int r = 0; r < 4; r++) sdA[r] = 1.0f / __shfl(sdq1, lg * 4 + r);
#pragma unroll
    for (int n = 0; n < 4; n++)
#pragma unroll
      for (int r = 0; r < 4; r++) {
        const int i = qt * 128 + 64 + w * 16 + lg * 4 + r;
        const int d = h * 64 + n * 16 + lr;
        qkv[((size_t)(b * 512 + i)) * 3072 + d] = f2bf(acc1[n][r] * sdA[r]);
      }
  }
}

// ---------------------------------------------------------------------------
// LN (bf16 residual): x = h(bf16) + delta(bf16) in f32; y = LN(x)*w + b.
// FINAL=0: writes hout (bf16, aliases h).  FINAL=1: writes fout (f32 d_out).
// ---------------------------------------------------------------------------
template<int FINAL>
__global__ __launch_bounds__(256)
void te_ln(const uint16_t* __restrict__ h, const uint16_t* __restrict__ delta,
           const float* __restrict__ w, const float* __restrict__ b,
           uint16_t* __restrict__ hout, float* __restrict__ fout)
{
  const int row = blockIdx.x, t = threadIdx.x;
  const size_t base = (size_t)row * 1024 + t * 4;
  u16x4 hv = *(const u16x4*)&h[base];
  u16x4 dv = *(const u16x4*)&delta[base];
  float x[4];
#pragma unroll
  for (int i = 0; i < 4; i++) x[i] = bf2f(hv[i]) + bf2f(dv[i]);
  float s = x[0] + x[1] + x[2] + x[3];
  float ss = x[0]*x[0] + x[1]*x[1] + x[2]*x[2] + x[3]*x[3];
#pragma unroll
  for (int msk = 32; msk >= 1; msk >>= 1) {
    s  += __shfl_xor(s, msk);
    ss += __shfl_xor(ss, msk);
  }
  __shared__ float rs[4], rq[4];
  const int wv = t >> 6;
  if ((t & 63) == 0) { rs[wv] = s; rq[wv] = ss; }
  __syncthreads();
  s  = rs[0] + rs[1] + rs[2] + rs[3];
  ss = rq[0] + rq[1] + rq[2] + rq[3];
  const float mean = s * (1.0f / 1024.0f);
  const float var  = ss * (1.0f / 1024.0f) - mean * mean;
  const float rstd = rsqrtf(var + 1e-5f);
  f32x4 wv4 = *(const f32x4*)&w[t * 4];
  f32x4 bv4 = *(const f32x4*)&b[t * 4];
  if (FINAL == 0) {
    u16x4 bo;
#pragma unroll
    for (int i = 0; i < 4; i++)
      bo[i] = f2bf((x[i] - mean) * rstd * wv4[i] + bv4[i]);
    *(u16x4*)&hout[base] = bo;
  } else {
    f32x4 yo;
#pragma unroll
    for (int i = 0; i < 4; i++)
      yo[i] = (x[i] - mean) * rstd * wv4[i] + bv4[i];
    *(f32x4*)&fout[base] = yo;
  }
}

// ---------------------------------------------------------------------------
extern "C" void kernel_launch(void* const* d_in, const int* in_sizes, int n_in,
                              void* d_out, int out_size, void* d_ws, size_t ws_size,
                              hipStream_t stream)
{
  (void)in_sizes; (void)n_in; (void)out_size; (void)ws_size;
  const float* x     = (const float*)d_in[0];
  const float* bn_w  = (const float*)d_in[1];
  const float* bn_b  = (const float*)d_in[2];
  const float* qkv_w = (const float*)d_in[3];
  const float* qkv_b = (const float*)d_in[4];
  const float* out_w = (const float*)d_in[5];
  const float* out_b = (const float*)d_in[6];
  const float* ln1_w = (const float*)d_in[7];
  const float* ln1_b = (const float*)d_in[8];
  const float* ln2_w = (const float*)d_in[9];
  const float* ln2_b = (const float*)d_in[10];
  const float* ff1_w = (const float*)d_in[11];
  const float* ff1_b = (const float*)d_in[12];
  const float* ff2_w = (const float*)d_in[13];
  const float* ff2_b = (const float*)d_in[14];

  char* ws = (char*)d_ws;
  uint16_t* h_bf    = (uint16_t*)ws;                      // 16 MiB @ 0
  uint16_t* qkvb    = (uint16_t*)(ws + (16u  << 20));     // 48 MiB @ 16
  uint16_t* scrA    = (uint16_t*)(ws + (64u  << 20));     // 16 MiB @ 64 (also x_bf)
  uint16_t* qkvw_bf = (uint16_t*)(ws + (80u  << 20));     // 36 MiB @ 80
  uint16_t* ff2w_bf = (uint16_t*)(ws + (116u << 20));     // 12 MiB @ 116
  uint16_t* bnw_bf  = (uint16_t*)(ws + (128u << 20));     //  2 MiB @ 128 (130 total)
  // d_out as scratch for weights that die before the final LN writes d_out:
  uint16_t* outw_bf = (uint16_t*)d_out;                   // 12 MiB @ 0
  uint16_t* ff1w_bf = (uint16_t*)((char*)d_out + (12u << 20)); // 12 MiB @ 12
  float*    outf    = (float*)d_out;                      // final fp32 output

  dim3 blk(256);
  dim3 blk512(512);

  // one-time fp32 -> bf16 conversions (weights + x)
  te_cvt<<<dim3(18874368 / 2048), blk, 0, stream>>>(qkv_w, qkvw_bf);
  te_cvt<<<dim3(6291456  / 2048), blk, 0, stream>>>(out_w, outw_bf);
  te_cvt<<<dim3(6291456  / 2048), blk, 0, stream>>>(ff1_w, ff1w_bf);
  te_cvt<<<dim3(6291456  / 2048), blk, 0, stream>>>(ff2_w, ff2w_bf);
  te_cvt<<<dim3(1048576  / 2048), blk, 0, stream>>>(bn_w,  bnw_bf);
  te_cvt<<<dim3(8388608  / 2048), blk, 0, stream>>>(x,     scrA);

  // bottleneck: h0 = x @ bn_w^T + bn_b  (bf16 residual)
  te_gemm256<0><<<dim3(256), blk512, 0, stream>>>(scrA, 1024, bnw_bf, bn_b,
                                                  h_bf, 1024, 1024);

  for (int l = 0; l < 6; l++) {
    te_gemm256<0><<<dim3(768), blk512, 0, stream>>>(
        h_bf, 1024, qkvw_bf + (size_t)l * 3072 * 1024, qkv_b + l * 3072,
        qkvb, 3072, 1024);
    te_attn<<<dim3(256, 4), blk, 0, stream>>>(qkvb);
    te_gemm256<0><<<dim3(256), blk512, 0, stream>>>(
        qkvb, 3072, outw_bf + (size_t)l * 1024 * 1024, out_b + l * 1024,
        scrA, 1024, 1024);
    te_ln<0><<<dim3(8192), blk, 0, stream>>>(h_bf, scrA, ln1_w + l * 1024, ln1_b + l * 1024,
                                             h_bf, nullptr);
    te_gemm256<2><<<dim3(256), blk512, 0, stream>>>(
        h_bf, 1024, ff1w_bf + (size_t)l * 1024 * 1024, ff1_b + l * 1024,
        scrA, 1024, 1024);
    te_gemm256<0><<<dim3(256), blk512, 0, stream>>>(
        scrA, 1024, ff2w_bf + (size_t)l * 1024 * 1024, ff2_b + l * 1024,
        qkvb, 1024, 1024);
    if (l == 5) {
      te_ln<1><<<dim3(8192), blk, 0, stream>>>(h_bf, qkvb, ln2_w + l * 1024, ln2_b + l * 1024,
                                               nullptr, outf);
    } else {
      te_ln<0><<<dim3(8192), blk, 0, stream>>>(h_bf, qkvb, ln2_w + l * 1024, ln2_b + l * 1024,
                                               h_bf, nullptr);
    }
  }
}

// Round 9
// 1386.390 us; speedup vs baseline: 1.4550x; 1.0124x over previous
//
#include <hip/hip_runtime.h>
#include <stdint.h>

#define DEV static __device__ __forceinline__

typedef __attribute__((ext_vector_type(8))) uint16_t u16x8;
typedef __attribute__((ext_vector_type(4))) uint16_t u16x4;
typedef __attribute__((ext_vector_type(4))) uint32_t u32x4;
typedef __attribute__((ext_vector_type(4))) float    f32x4;
typedef __attribute__((ext_vector_type(8))) __bf16   bf16x8;

typedef __attribute__((address_space(3))) void lds_void;
typedef __attribute__((address_space(1))) void gbl_void;

DEV float bf2f(uint16_t u){
  union { uint32_t i; float f; } v; v.i = ((uint32_t)u) << 16; return v.f;
}
DEV uint16_t f2bf(float f){ return __builtin_bit_cast(uint16_t, (__bf16)f); }
DEV f32x4 mfma16(u16x8 a, u16x8 b, f32x4 c){
  return __builtin_amdgcn_mfma_f32_16x16x32_bf16(
      __builtin_bit_cast(bf16x8, a), __builtin_bit_cast(bf16x8, b), c, 0, 0, 0);
}
DEV uint32_t cvt_pk_bf16(float lo, float hi){
  uint32_t r;
  asm("v_cvt_pk_bf16_f32 %0, %1, %2" : "=v"(r) : "v"(lo), "v"(hi));
  return r;
}

// ---------------------------------------------------------------------------
// fp32 -> bf16 elementwise convert, 8 elems/thread.
// ---------------------------------------------------------------------------
__global__ __launch_bounds__(256)
void te_cvt(const float* __restrict__ in, uint16_t* __restrict__ out)
{
  const size_t i = ((size_t)blockIdx.x * 256 + threadIdx.x) * 8;
  f32x4 a = *(const f32x4*)(in + i);
  f32x4 b = *(const f32x4*)(in + i + 4);
  u16x8 o;
#pragma unroll
  for (int e = 0; e < 4; e++) {
    o[e]     = f2bf(a[e]);
    o[e + 4] = f2bf(b[e]);
  }
  *(u16x8*)(out + i) = o;
}

// ---------------------------------------------------------------------------
// Deep-pipelined GEMM v2: out[M=8192,N] = A[M,K](lda)@W[N,K]^T + bias
// 256x128 block, BK=64, 512 thr = 8 waves (4M x 2N, wave tile 64x64).
// Triple-buffered LDS (144 KB), 2-deep prefetch, counted vmcnt(12/6/0),
// 2 raw s_barriers per K-tile, T2 chunk-XOR swizzle, bijective XCD swizzle.
// MODE 0: bias -> bf16.  MODE 2: bias + GELU(tanh) -> bf16.
// ---------------------------------------------------------------------------
template<int MODE>
__global__ __launch_bounds__(512)
void te_gemm256(const uint16_t* __restrict__ A, int lda,
                const uint16_t* __restrict__ Wm, const float* __restrict__ bias,
                uint16_t* __restrict__ outB, int N, int K)
{
  constexpr int SZA = 256 * 64;           // A tile elems
  constexpr int SZB = 128 * 64;           // B tile elems
  __shared__ uint16_t lds[3 * (SZA + SZB)];   // 144 KiB

  const int tid = threadIdx.x;
  const int w = tid >> 6, l = tid & 63;
  const int lr = l & 15, lg = l >> 4;
  const int wr = w >> 1, wc = w & 1;      // 4M x 2N wave grid, 64x64 tiles
  const int srow = l >> 3, chunk = l & 7;

  // bijective XCD swizzle on flat block id (gridDim.x % 8 == 0)
  const int nb = gridDim.x;
  const int bid = blockIdx.x;
  const int lid = (bid & 7) * (nb >> 3) + (bid >> 3);
  const int nx = N >> 7;
  const int tm = (lid / nx) << 8;
  const int tn = (lid % nx) << 7;

  const int rw = w * 8 + srow;            // 0..63 stage row within 64-row group
  const int sc = (chunk ^ srow) << 3;     // pre-swizzled source col chunk

  auto stage = [&](int kt, int p) {
    const int k0 = kt << 6;
    uint16_t* bufA = lds + p * (SZA + SZB);
    uint16_t* bufB = bufA + SZA;
#pragma unroll
    for (int c = 0; c < 4; c++) {
      const uint16_t* ga = A + (size_t)(tm + c * 64 + rw) * lda + (k0 + sc);
      __builtin_amdgcn_global_load_lds((gbl_void*)(uintptr_t)ga,
          (lds_void*)(bufA + (c * 64 + w * 8) * 64), 16, 0, 0);
    }
#pragma unroll
    for (int c = 0; c < 2; c++) {
      const uint16_t* gw = Wm + (size_t)(tn + c * 64 + rw) * K + (k0 + sc);
      __builtin_amdgcn_global_load_lds((gbl_void*)(uintptr_t)gw,
          (lds_void*)(bufB + (c * 64 + w * 8) * 64), 16, 0, 0);
    }
  };

  f32x4 acc[4][4] = {};
  const int nt = K >> 6;

  stage(0, 0);
  stage(1, 1);
  for (int t = 0; t < nt; ++t) {
    const int cur = t % 3;
    uint16_t* bufA = lds + cur * (SZA + SZB);
    uint16_t* bufB = bufA + SZA;

    asm volatile("" ::: "memory");
    if (t + 2 < nt) {
      stage(t + 2, (t + 2) % 3);
      asm volatile("s_waitcnt vmcnt(12)" ::: "memory");   // tile t landed
    } else if (t + 1 < nt) {
      asm volatile("s_waitcnt vmcnt(6)" ::: "memory");
    } else {
      asm volatile("s_waitcnt vmcnt(0)" ::: "memory");
    }
    __builtin_amdgcn_s_barrier();         // tile t visible to all waves

#pragma unroll
    for (int kk = 0; kk < 2; kk++) {
      u16x8 af[4], bfr[2];
#pragma unroll
      for (int i = 0; i < 4; i++) {
        const int row = wr * 64 + i * 16 + lr;
        af[i] = *(const u16x8*)&bufA[row * 64 + (((kk * 4 + lg) ^ (lr & 7)) << 3)];
      }
#pragma unroll
      for (int j = 0; j < 2; j++) {
        const int row = wc * 64 + j * 16 + lr;
        bfr[j] = *(const u16x8*)&bufB[row * 64 + (((kk * 4 + lg) ^ (lr & 7)) << 3)];
      }
      u16x8 bfr2[2];
#pragma unroll
      for (int j = 0; j < 2; j++) {
        const int row = wc * 64 + (j + 2) * 16 + lr;
        bfr2[j] = *(const u16x8*)&bufB[row * 64 + (((kk * 4 + lg) ^ (lr & 7)) << 3)];
      }
      __builtin_amdgcn_s_setprio(1);
#pragma unroll
      for (int i = 0; i < 4; i++) {
        acc[i][0] = mfma16(af[i], bfr[0],  acc[i][0]);
        acc[i][1] = mfma16(af[i], bfr[1],  acc[i][1]);
        acc[i][2] = mfma16(af[i], bfr2[0], acc[i][2]);
        acc[i][3] = mfma16(af[i], bfr2[1], acc[i][3]);
      }
      __builtin_amdgcn_s_setprio(0);
    }
    __builtin_amdgcn_s_barrier();         // reads of buf cur complete
  }

  // epilogue
  float bv[4];
#pragma unroll
  for (int j = 0; j < 4; j++) bv[j] = bias[tn + wc * 64 + j * 16 + lr];
#pragma unroll
  for (int i = 0; i < 4; i++)
#pragma unroll
    for (int j = 0; j < 4; j++)
#pragma unroll
      for (int r = 0; r < 4; r++) {
        const int row = tm + wr * 64 + i * 16 + lg * 4 + r;
        const int col = tn + wc * 64 + j * 16 + lr;
        float v = acc[i][j][r] + bv[j];
        if (MODE == 2) {
          const float u = 0.7978845608028654f * v * (1.0f + 0.044715f * v * v);
          const float t = 1.0f - 2.0f / (__expf(2.0f * u) + 1.0f);
          v = 0.5f * v * (1.0f + t);
        }
        outB[(size_t)row * N + col] = f2bf(v);
      }
}

// ---------------------------------------------------------------------------
// softmax + pack macro (per q-group), S^T layout: lane lr owns q-row iQ.
// ---------------------------------------------------------------------------
#define SOFTMAX_PACK(S, MR, SDQ, ACC, IQ, P2)                                  \
  {                                                                            \
    const float f0 = (float)((IQ) - jt - lg * 4);                              \
    float mt = -1e30f;                                                         \
    _Pragma("unroll")                                                          \
    for (int n = 0; n < 4; n++) {                                              \
      const float fj = f0 - (float)(n * 16);                                   \
      _Pragma("unroll")                                                        \
      for (int r = 0; r < 4; r++) {                                            \
        const float v = fmaf(S[n][r], scl2e, -slope2e * fabsf(fj - (float)r)); \
        S[n][r] = v;                                                           \
        mt = fmaxf(mt, v);                                                     \
      }                                                                        \
    }                                                                          \
    mt = fmaxf(mt, __shfl_xor(mt, 16));                                        \
    mt = fmaxf(mt, __shfl_xor(mt, 32));                                        \
    if (!__all(mt <= MR)) {                                                    \
      const float mN = fmaxf(MR, mt);                                          \
      const float fq = exp2f(MR - mN);                                         \
      MR = mN;                                                                 \
      SDQ *= fq;                                                               \
      float fA[4];                                                             \
      _Pragma("unroll")                                                        \
      for (int r = 0; r < 4; r++) fA[r] = __shfl(fq, lg * 4 + r);              \
      _Pragma("unroll")                                                        \
      for (int n = 0; n < 4; n++)                                              \
        _Pragma("unroll")                                                      \
        for (int r = 0; r < 4; r++) ACC[n][r] *= fA[r];                        \
    }                                                                          \
    float rs = 0.0f;                                                           \
    _Pragma("unroll")                                                          \
    for (int n = 0; n < 4; n++)                                                \
      _Pragma("unroll")                                                        \
      for (int r = 0; r < 4; r++) {                                            \
        const float p = exp2f(S[n][r] - MR);                                   \
        S[n][r] = p;                                                           \
        rs += p;                                                               \
      }                                                                        \
    rs += __shfl_xor(rs, 16);                                                  \
    rs += __shfl_xor(rs, 32);                                                  \
    SDQ += rs;                                                                 \
    _Pragma("unroll")                                                          \
    for (int n = 0; n < 4; n++) {                                              \
      P2[n][0] = cvt_pk_bf16(S[n][0], S[n][1]);                                \
      P2[n][1] = cvt_pk_bf16(S[n][2], S[n][3]);                                \
    }                                                                          \
  }

// ---------------------------------------------------------------------------
// Fused attention v3: QBLK=128 (2 q-groups/block, staging amortized 2x).
// Swapped QK^T, exp2 domain, exact defer-max (diag-first), in-register P.
// qkv [B*T, 3072] bf16; grid (bh=256, qt=4). In-place q output.
// ---------------------------------------------------------------------------
__global__ __launch_bounds__(256)
void te_attn(uint16_t* __restrict__ qkv)
{
  __shared__ uint16_t kl[64 * 64];   // K[j][d] swizzled chunks
  __shared__ uint16_t vt[64 * 64];   // V^T[d][j] swizzled chunks
  const int tid = threadIdx.x;
  const int w = tid >> 6, l = tid & 63;
  const int lr = l & 15, lg = l >> 4;
  const int bh = blockIdx.x, qt = blockIdx.y;   // qt 0..3
  const int h = bh & 15, b = bh >> 4;

  const int iQ0 = qt * 128 + w * 16 + lr;       // group 0; group 1 = +64
  u16x8 qf[2][2];
#pragma unroll
  for (int g = 0; g < 2; g++) {
    const size_t qoff = ((size_t)(b * 512 + iQ0 + g * 64)) * 3072 + h * 64 + lg * 8;
    qf[g][0] = *(const u16x8*)&qkv[qoff];
    qf[g][1] = *(const u16x8*)&qkv[qoff + 32];
  }
  const float LOG2E = 1.4426950408889634f;
  const float scl2e = 0.125f * LOG2E;
  const float slope2e = exp2f(-0.5f * (float)(h + 1)) * LOG2E;

  const int sjb = tid >> 3;           // 0..31 (j within half-tile)
  const int sd0 = (tid & 7) * 8;      // d chunk start

  float mR0 = -1e30f, sdq0 = 0.0f, mR1 = -1e30f, sdq1 = 0.0f;
  f32x4 acc0[4] = {}, acc1[4] = {};

  // prologue: load first (diagonal-of-group-0) tile into regs
  u16x8 kreg[2], vreg[2];
  {
    const int jt0 = (qt * 2) * 64;
#pragma unroll
    for (int cc = 0; cc < 2; cc++) {
      const int j = sjb + cc * 32;
      const size_t rbase = ((size_t)(b * 512 + jt0 + j)) * 3072 + h * 64 + sd0;
      kreg[cc] = *(const u16x8*)&qkv[rbase + 1024];
      vreg[cc] = *(const u16x8*)&qkv[rbase + 2048];
    }
  }

  for (int step = 0; step < 8; step++) {
    const int jt = ((qt * 2 + step) & 7) * 64;
    // ---- write staged regs to LDS ----
#pragma unroll
    for (int cc = 0; cc < 2; cc++) {
      const int j = sjb + cc * 32;
      *(u16x8*)&kl[j * 64 + (((sd0 >> 3) ^ (j & 7)) << 3)] = kreg[cc];
      const int cV = (((j >> 3) ^ (sd0 >> 3)) << 3) + (j & 7);
#pragma unroll
      for (int e = 0; e < 8; e++) vt[(sd0 + e) * 64 + cV] = vreg[cc][e];
    }
    __syncthreads();
    // ---- issue next tile's global loads (hidden under compute) ----
    if (step < 7) {
      const int jtn = ((qt * 2 + step + 1) & 7) * 64;
#pragma unroll
      for (int cc = 0; cc < 2; cc++) {
        const int j = sjb + cc * 32;
        const size_t rbase = ((size_t)(b * 512 + jtn + j)) * 3072 + h * 64 + sd0;
        kreg[cc] = *(const u16x8*)&qkv[rbase + 1024];
        vreg[cc] = *(const u16x8*)&qkv[rbase + 2048];
      }
    }

    // ---- S^T = mfma(K, Q) for both q-groups (K-frags shared) ----
    f32x4 s0[4] = {}, s1[4] = {};
#pragma unroll
    for (int kk = 0; kk < 2; kk++) {
      u16x8 kf[4];
#pragma unroll
      for (int n = 0; n < 4; n++) {
        const int row = n * 16 + lr;
        kf[n] = *(const u16x8*)&kl[row * 64 + (((kk * 4 + lg) ^ (lr & 7)) << 3)];
      }
      __builtin_amdgcn_s_setprio(1);
#pragma unroll
      for (int n = 0; n < 4; n++) {
        s0[n] = mfma16(kf[n], qf[0][kk], s0[n]);
        s1[n] = mfma16(kf[n], qf[1][kk], s1[n]);
      }
      __builtin_amdgcn_s_setprio(0);
    }

    // ---- softmax + pack per group ----
    uint32_t P2a[4][2], P2b[4][2];
    SOFTMAX_PACK(s0, mR0, sdq0, acc0, iQ0,      P2a);
    SOFTMAX_PACK(s1, mR1, sdq1, acc1, iQ0 + 64, P2b);

    // ---- redistribute to A-frag layout + PV (V-frags shared) ----
#pragma unroll
    for (int kk = 0; kk < 2; kk++) {
      uint32_t pw0[4], pw1[4];
#pragma unroll
      for (int t = 0; t < 4; t++) {
        const int srcLane = lr + 16 * ((lg & 1) * 2 + (t >> 1));
        const uint32_t a0 = __shfl(P2a[2 * kk + 0][t & 1], srcLane);
        const uint32_t b0 = __shfl(P2a[2 * kk + 1][t & 1], srcLane);
        pw0[t] = (lg >> 1) ? b0 : a0;
        const uint32_t a1 = __shfl(P2b[2 * kk + 0][t & 1], srcLane);
        const uint32_t b1 = __shfl(P2b[2 * kk + 1][t & 1], srcLane);
        pw1[t] = (lg >> 1) ? b1 : a1;
      }
      u32x4 q0 = { pw0[0], pw0[1], pw0[2], pw0[3] };
      u32x4 q1 = { pw1[0], pw1[1], pw1[2], pw1[3] };
      u16x8 pf0 = __builtin_bit_cast(u16x8, q0);
      u16x8 pf1 = __builtin_bit_cast(u16x8, q1);
      u16x8 vf[4];
#pragma unroll
      for (int n = 0; n < 4; n++) {
        const int row = n * 16 + lr;
        vf[n] = *(const u16x8*)&vt[row * 64 + ((((kk * 4 + lg) ^ (2 * n + (lr >> 3))) & 7) << 3)];
      }
      __builtin_amdgcn_s_setprio(1);
#pragma unroll
      for (int n = 0; n < 4; n++) {
        acc0[n] = mfma16(pf0, vf[n], acc0[n]);
        acc1[n] = mfma16(pf1, vf[n], acc1[n]);
      }
      __builtin_amdgcn_s_setprio(0);
    }
    __syncthreads();
  }

  // ---- epilogue: O[i][d] for both groups ----
  {
    float sdA[4];
#pragma unroll
    for (int r = 0; r < 4; r++) sdA[r] = 1.0f / __shfl(sdq0, lg * 4 + r);
#pragma unroll
    for (int n = 0; n < 4; n++)
#pragma unroll
      for (int r = 0; r < 4; r++) {
        const int i = qt * 128 + w * 16 + lg * 4 + r;
        const int d = h * 64 + n * 16 + lr;
        qkv[((size_t)(b * 512 + i)) * 3072 + d] = f2bf(acc0[n][r] * sdA[r]);
      }
  }
  {
    float sdA[4];
#pragma unroll
    for (int r = 0; r < 4; r++) sdA[r] = 1.0f / __shfl(sdq1, lg * 4 + r);
#pragma unroll
    for (int n = 0; n < 4; n++)
#pragma unroll
      for (int r = 0; r < 4; r++) {
        const int i = qt * 128 + 64 + w * 16 + lg * 4 + r;
        const int d = h * 64 + n * 16 + lr;
        qkv[((size_t)(b * 512 + i)) * 3072 + d] = f2bf(acc1[n][r] * sdA[r]);
      }
  }
}

// ---------------------------------------------------------------------------
// LN (bf16 residual): x = h(bf16) + delta(bf16) in f32; y = LN(x)*w + b.
// FINAL=0: writes hout (bf16, aliases h).  FINAL=1: writes fout (f32 d_out).
// ---------------------------------------------------------------------------
template<int FINAL>
__global__ __launch_bounds__(256)
void te_ln(const uint16_t* __restrict__ h, const uint16_t* __restrict__ delta,
           const float* __restrict__ w, const float* __restrict__ b,
           uint16_t* __restrict__ hout, float* __restrict__ fout)
{
  const int row = blockIdx.x, t = threadIdx.x;
  const size_t base = (size_t)row * 1024 + t * 4;
  u16x4 hv = *(const u16x4*)&h[base];
  u16x4 dv = *(const u16x4*)&delta[base];
  float x[4];
#pragma unroll
  for (int i = 0; i < 4; i++) x[i] = bf2f(hv[i]) + bf2f(dv[i]);
  float s = x[0] + x[1] + x[2] + x[3];
  float ss = x[0]*x[0] + x[1]*x[1] + x[2]*x[2] + x[3]*x[3];
#pragma unroll
  for (int msk = 32; msk >= 1; msk >>= 1) {
    s  += __shfl_xor(s, msk);
    ss += __shfl_xor(ss, msk);
  }
  __shared__ float rs[4], rq[4];
  const int wv = t >> 6;
  if ((t & 63) == 0) { rs[wv] = s; rq[wv] = ss; }
  __syncthreads();
  s  = rs[0] + rs[1] + rs[2] + rs[3];
  ss = rq[0] + rq[1] + rq[2] + rq[3];
  const float mean = s * (1.0f / 1024.0f);
  const float var  = ss * (1.0f / 1024.0f) - mean * mean;
  const float rstd = rsqrtf(var + 1e-5f);
  f32x4 wv4 = *(const f32x4*)&w[t * 4];
  f32x4 bv4 = *(const f32x4*)&b[t * 4];
  if (FINAL == 0) {
    u16x4 bo;
#pragma unroll
    for (int i = 0; i < 4; i++)
      bo[i] = f2bf((x[i] - mean) * rstd * wv4[i] + bv4[i]);
    *(u16x4*)&hout[base] = bo;
  } else {
    f32x4 yo;
#pragma unroll
    for (int i = 0; i < 4; i++)
      yo[i] = (x[i] - mean) * rstd * wv4[i] + bv4[i];
    *(f32x4*)&fout[base] = yo;
  }
}

// ---------------------------------------------------------------------------
extern "C" void kernel_launch(void* const* d_in, const int* in_sizes, int n_in,
                              void* d_out, int out_size, void* d_ws, size_t ws_size,
                              hipStream_t stream)
{
  (void)in_sizes; (void)n_in; (void)out_size; (void)ws_size;
  const float* x     = (const float*)d_in[0];
  const float* bn_w  = (const float*)d_in[1];
  const float* bn_b  = (const float*)d_in[2];
  const float* qkv_w = (const float*)d_in[3];
  const float* qkv_b = (const float*)d_in[4];
  const float* out_w = (const float*)d_in[5];
  const float* out_b = (const float*)d_in[6];
  const float* ln1_w = (const float*)d_in[7];
  const float* ln1_b = (const float*)d_in[8];
  const float* ln2_w = (const float*)d_in[9];
  const float* ln2_b = (const float*)d_in[10];
  const float* ff1_w = (const float*)d_in[11];
  const float* ff1_b = (const float*)d_in[12];
  const float* ff2_w = (const float*)d_in[13];
  const float* ff2_b = (const float*)d_in[14];

  char* ws = (char*)d_ws;
  uint16_t* h_bf    = (uint16_t*)ws;                      // 16 MiB @ 0
  uint16_t* qkvb    = (uint16_t*)(ws + (16u  << 20));     // 48 MiB @ 16
  uint16_t* scrA    = (uint16_t*)(ws + (64u  << 20));     // 16 MiB @ 64 (also x_bf)
  uint16_t* qkvw_bf = (uint16_t*)(ws + (80u  << 20));     // 36 MiB @ 80
  uint16_t* ff2w_bf = (uint16_t*)(ws + (116u << 20));     // 12 MiB @ 116
  uint16_t* bnw_bf  = (uint16_t*)(ws + (128u << 20));     //  2 MiB @ 128 (130 total)
  // d_out as scratch for weights that die before the final LN writes d_out:
  uint16_t* outw_bf = (uint16_t*)d_out;                   // 12 MiB @ 0
  uint16_t* ff1w_bf = (uint16_t*)((char*)d_out + (12u << 20)); // 12 MiB @ 12
  float*    outf    = (float*)d_out;                      // final fp32 output

  dim3 blk(256);
  dim3 blk512(512);

  // one-time fp32 -> bf16 conversions (weights + x)
  te_cvt<<<dim3(18874368 / 2048), blk, 0, stream>>>(qkv_w, qkvw_bf);
  te_cvt<<<dim3(6291456  / 2048), blk, 0, stream>>>(out_w, outw_bf);
  te_cvt<<<dim3(6291456  / 2048), blk, 0, stream>>>(ff1_w, ff1w_bf);
  te_cvt<<<dim3(6291456  / 2048), blk, 0, stream>>>(ff2_w, ff2w_bf);
  te_cvt<<<dim3(1048576  / 2048), blk, 0, stream>>>(bn_w,  bnw_bf);
  te_cvt<<<dim3(8388608  / 2048), blk, 0, stream>>>(x,     scrA);

  // bottleneck: h0 = x @ bn_w^T + bn_b  (bf16 residual)
  te_gemm256<0><<<dim3(256), blk512, 0, stream>>>(scrA, 1024, bnw_bf, bn_b,
                                                  h_bf, 1024, 1024);

  for (int l = 0; l < 6; l++) {
    te_gemm256<0><<<dim3(768), blk512, 0, stream>>>(
        h_bf, 1024, qkvw_bf + (size_t)l * 3072 * 1024, qkv_b + l * 3072,
        qkvb, 3072, 1024);
    te_attn<<<dim3(256, 4), blk, 0, stream>>>(qkvb);
    te_gemm256<0><<<dim3(256), blk512, 0, stream>>>(
        qkvb, 3072, outw_bf + (size_t)l * 1024 * 1024, out_b + l * 1024,
        scrA, 1024, 1024);
    te_ln<0><<<dim3(8192), blk, 0, stream>>>(h_bf, scrA, ln1_w + l * 1024, ln1_b + l * 1024,
                                             h_bf, nullptr);
    te_gemm256<2><<<dim3(256), blk512, 0, stream>>>(
        h_bf, 1024, ff1w_bf + (size_t)l * 1024 * 1024, ff1_b + l * 1024,
        scrA, 1024, 1024);
    te_gemm256<0><<<dim3(256), blk512, 0, stream>>>(
        scrA, 1024, ff2w_bf + (size_t)l * 1024 * 1024, ff2_b + l * 1024,
        qkvb, 1024, 1024);
    if (l == 5) {
      te_ln<1><<<dim3(8192), blk, 0, stream>>>(h_bf, qkvb, ln2_w + l * 1024, ln2_b + l * 1024,
                                               nullptr, outf);
    } else {
      te_ln<0><<<dim3(8192), blk, 0, stream>>>(h_bf, qkvb, ln2_w + l * 1024, ln2_b + l * 1024,
                                               h_bf, nullptr);
    }
  }
}